// Round 1
// baseline (614.895 us; speedup 1.0000x reference)
//
#include <hip/hip_runtime.h>

#define NN 50000
#define NE 800000
#define D 96
#define NL 3
#define NC 10
#define BN_EPS 1e-5f

// ---------------- edge index access (int32 vs int64 auto-detect) -------------
__device__ __forceinline__ int edge_at(const void* idx, int is64, long long pos) {
    if (is64) return (int)((const long long*)idx)[pos];
    return ((const int*)idx)[pos];
}

// Detect whether edge_index is stored as int64 (high 32-bit words all zero)
__global__ void detect_kernel(const int* __restrict__ words, int* __restrict__ flag) {
    __shared__ int any_nz;
    if (threadIdx.x == 0) any_nz = 0;
    __syncthreads();
    int v = words[2 * threadIdx.x + 1];
    if (v != 0) atomicOr(&any_nz, 1);
    __syncthreads();
    if (threadIdx.x == 0) *flag = any_nz ? 0 : 1;   // 1 => int64
}

__global__ void zero_kernel(int* __restrict__ deg, float* __restrict__ stats,
                            int ndeg, int nstats) {
    int i = blockIdx.x * blockDim.x + threadIdx.x;
    if (i < ndeg) deg[i] = 0;
    if (i < nstats) stats[i] = 0.f;
}

__global__ void deg_kernel(const void* __restrict__ idx, const int* __restrict__ flag,
                           int* __restrict__ deg, int E) {
    int e = blockIdx.x * blockDim.x + threadIdx.x;
    if (e >= E) return;
    int is64 = *flag;
    int d = edge_at(idx, is64, (long long)E + e);
    atomicAdd(&deg[d], 1);
}

// single-block exclusive scan (shfl-based), also writes fill counters + inv_deg
__global__ void scan_kernel(const int* __restrict__ deg, int* __restrict__ row_ptr,
                            int* __restrict__ fill_ctr, float* __restrict__ inv_deg, int n) {
    __shared__ int wsum[16];
    __shared__ int s_run;
    int tid = threadIdx.x;
    int lane = tid & 63;
    int w = tid >> 6;
    if (tid == 0) s_run = 0;
    __syncthreads();
    for (int base = 0; base < n; base += 1024) {
        int i = base + tid;
        int v = (i < n) ? deg[i] : 0;
        int x = v;
        #pragma unroll
        for (int off = 1; off < 64; off <<= 1) {
            int y = __shfl_up(x, off);
            if (lane >= off) x += y;
        }
        if (lane == 63) wsum[w] = x;
        __syncthreads();
        if (w == 0) {
            int t = (lane < 16) ? wsum[lane] : 0;
            #pragma unroll
            for (int off = 1; off < 16; off <<= 1) {
                int y = __shfl_up(t, off);
                if (lane >= off) t += y;
            }
            if (lane < 16) wsum[lane] = t;
        }
        __syncthreads();
        int run = s_run;
        int wofs = (w > 0) ? wsum[w - 1] : 0;
        int excl = run + wofs + x - v;
        if (i < n) {
            row_ptr[i] = excl;
            fill_ctr[i] = excl;
            inv_deg[i] = 1.0f / (float)(v > 0 ? v : 1);
        }
        __syncthreads();
        if (tid == 0) s_run = run + wsum[15];
        __syncthreads();
    }
    if (tid == 0) row_ptr[n] = s_run;
}

__global__ void fill_kernel(const void* __restrict__ idx, const int* __restrict__ flag,
                            int* __restrict__ fill_ctr, int* __restrict__ csr_src, int E) {
    int e = blockIdx.x * blockDim.x + threadIdx.x;
    if (e >= E) return;
    int is64 = *flag;
    int s = edge_at(idx, is64, e);
    int d = edge_at(idx, is64, (long long)E + e);
    int pos = atomicAdd(&fill_ctr[d], 1);
    csr_src[pos] = s;
}

// one wave per dst node: mean-aggregate neighbor rows (no atomics)
__global__ void agg_kernel(const float* __restrict__ h, const int* __restrict__ row_ptr,
                           const int* __restrict__ csr_src, const float* __restrict__ inv_deg,
                           float* __restrict__ agg, int n) {
    int gid = blockIdx.x * blockDim.x + threadIdx.x;
    int node = gid >> 6;
    int lane = gid & 63;
    if (node >= n) return;
    int beg = row_ptr[node], end = row_ptr[node + 1];
    float a0 = 0.f, a1 = 0.f, b0 = 0.f, b1 = 0.f;
    int e = beg;
    for (; e + 1 < end; e += 2) {
        int s0 = csr_src[e];
        int s1 = csr_src[e + 1];
        const float* r0 = h + (size_t)s0 * D;
        const float* r1 = h + (size_t)s1 * D;
        a0 += r0[lane];
        b0 += r1[lane];
        if (lane < 32) {
            a1 += r0[64 + lane];
            b1 += r1[64 + lane];
        }
    }
    if (e < end) {
        int s0 = csr_src[e];
        const float* r0 = h + (size_t)s0 * D;
        a0 += r0[lane];
        if (lane < 32) a1 += r0[64 + lane];
    }
    a0 += b0; a1 += b1;
    float idg = inv_deg[node];
    float* orow = agg + (size_t)node * D;
    orow[lane] = a0 * idg;
    if (lane < 32) orow[64 + lane] = a1 * idg;
}

// hout[n][f] = sum_k agg[n][k]*Wn[k][f] + hin[n][k]*Ws[k][f] + bias[f]
// block: (96,2) = 192 threads, 8 nodes per block, 4 nodes per thread
__global__ void __launch_bounds__(192) gemm_kernel(
        const float* __restrict__ hin, const float* __restrict__ aggv,
        const float* __restrict__ Wn, const float* __restrict__ Ws,
        const float* __restrict__ bias, float* __restrict__ hout, int n) {
    __shared__ float sh[8][D];
    __shared__ float sa[8][D];
    int f = threadIdx.x;      // 0..95
    int ty = threadIdx.y;     // 0..1
    int tid = f + D * ty;     // 0..191
    int node0 = blockIdx.x * 8;
    for (int i = tid; i < 8 * D; i += 192) {
        int nn = i / D, kk = i % D;
        int g = node0 + nn;
        sh[nn][kk] = (g < n) ? hin[(size_t)g * D + kk] : 0.f;
        sa[nn][kk] = (g < n) ? aggv[(size_t)g * D + kk] : 0.f;
    }
    __syncthreads();
    float b = bias[f];
    float acc0 = b, acc1 = b, acc2 = b, acc3 = b;
    int base = ty * 4;
    #pragma unroll 4
    for (int k = 0; k < D; ++k) {
        float wn = Wn[k * D + f];
        float ws = Ws[k * D + f];
        acc0 += sa[base + 0][k] * wn + sh[base + 0][k] * ws;
        acc1 += sa[base + 1][k] * wn + sh[base + 1][k] * ws;
        acc2 += sa[base + 2][k] * wn + sh[base + 2][k] * ws;
        acc3 += sa[base + 3][k] * wn + sh[base + 3][k] * ws;
    }
    int g0 = node0 + base;
    if (g0 + 0 < n) hout[(size_t)(g0 + 0) * D + f] = acc0;
    if (g0 + 1 < n) hout[(size_t)(g0 + 1) * D + f] = acc1;
    if (g0 + 2 < n) hout[(size_t)(g0 + 2) * D + f] = acc2;
    if (g0 + 3 < n) hout[(size_t)(g0 + 3) * D + f] = acc3;
}

// per-feature sum and sumsq partials -> global atomics
__global__ void bn_stats_kernel(const float* __restrict__ h, float* __restrict__ stats, int n) {
    __shared__ float ssum[4][D];
    __shared__ float ssq[4][D];
    int f = threadIdx.x, ty = threadIdx.y;
    float s = 0.f, q = 0.f;
    for (int r = blockIdx.x * 4 + ty; r < n; r += gridDim.x * 4) {
        float v = h[(size_t)r * D + f];
        s += v;
        q += v * v;
    }
    ssum[ty][f] = s;
    ssq[ty][f] = q;
    __syncthreads();
    if (ty == 0) {
        float ts = ssum[0][f] + ssum[1][f] + ssum[2][f] + ssum[3][f];
        float tq = ssq[0][f] + ssq[1][f] + ssq[2][f] + ssq[3][f];
        atomicAdd(&stats[f], ts);
        atomicAdd(&stats[D + f], tq);
    }
}

// normalize + affine + ReLU, in place, float4
__global__ void bn_apply_kernel(float* __restrict__ h, const float* __restrict__ stats,
                                const float* __restrict__ gamma, const float* __restrict__ beta,
                                int n) {
    int i = blockIdx.x * blockDim.x + threadIdx.x;
    int total = n * (D / 4);
    if (i >= total) return;
    int q = i % (D / 4);
    float4 v = ((const float4*)h)[i];
    float inv_n = 1.0f / (float)n;
    #pragma unroll
    for (int j = 0; j < 4; ++j) {
        int f = q * 4 + j;
        float mu = stats[f] * inv_n;
        float var = stats[D + f] * inv_n - mu * mu;
        float sc = rsqrtf(var + BN_EPS) * gamma[f];
        float val = ((&v.x)[j] - mu) * sc + beta[f];
        (&v.x)[j] = fmaxf(val, 0.f);
    }
    ((float4*)h)[i] = v;
}

__global__ void clf_kernel(const float* __restrict__ h, const float* __restrict__ W,
                           const float* __restrict__ b, float* __restrict__ out, int n) {
    __shared__ float sW[D * NC];
    __shared__ float sB[NC];
    int tid = threadIdx.x;
    for (int i = tid; i < D * NC; i += blockDim.x) sW[i] = W[i];
    if (tid < NC) sB[tid] = b[tid];
    __syncthreads();
    int node = blockIdx.x * blockDim.x + tid;
    if (node >= n) return;
    float acc[NC];
    #pragma unroll
    for (int c = 0; c < NC; ++c) acc[c] = sB[c];
    const float4* row = (const float4*)(h + (size_t)node * D);
    #pragma unroll 4
    for (int k4 = 0; k4 < D / 4; ++k4) {
        float4 v = row[k4];
        #pragma unroll
        for (int j = 0; j < 4; ++j) {
            float vv = (&v.x)[j];
            int k = k4 * 4 + j;
            #pragma unroll
            for (int c = 0; c < NC; ++c) acc[c] += vv * sW[k * NC + c];
        }
    }
    float* orow = out + (size_t)node * NC;
    #pragma unroll
    for (int c = 0; c < NC; ++c) orow[c] = acc[c];
}

extern "C" void kernel_launch(void* const* d_in, const int* in_sizes, int n_in,
                              void* d_out, int out_size, void* d_ws, size_t ws_size,
                              hipStream_t stream) {
    const float* x      = (const float*)d_in[0];
    const void*  eidx   = d_in[1];
    const float* w_ngh  = (const float*)d_in[2];
    const float* w_self = (const float*)d_in[3];
    const float* bias   = (const float*)d_in[4];
    const float* gamma  = (const float*)d_in[5];
    const float* beta   = (const float*)d_in[6];
    const float* clf_w  = (const float*)d_in[7];
    const float* clf_b  = (const float*)d_in[8];
    float* out = (float*)d_out;

    char* ws = (char*)d_ws;
    size_t o = 0;
    auto alloc = [&](size_t bytes) -> void* {
        void* r = ws + o;
        o += (bytes + 255) & ~(size_t)255;
        return r;
    };
    int*   flag     = (int*)alloc(4);
    int*   deg      = (int*)alloc((size_t)NN * 4);
    int*   row_ptr  = (int*)alloc((size_t)(NN + 1) * 4);
    int*   fill_ctr = (int*)alloc((size_t)NN * 4);
    float* inv_deg  = (float*)alloc((size_t)NN * 4);
    int*   csr_src  = (int*)alloc((size_t)NE * 4);
    float* stats    = (float*)alloc((size_t)NL * 2 * D * 4);
    float* h_a      = (float*)alloc((size_t)NN * D * 4);
    float* h_b      = (float*)alloc((size_t)NN * D * 4);
    float* agg      = (float*)alloc((size_t)NN * D * 4);

    detect_kernel<<<1, 256, 0, stream>>>((const int*)eidx, flag);
    zero_kernel<<<(NN + 255) / 256, 256, 0, stream>>>(deg, stats, NN, NL * 2 * D);
    deg_kernel<<<(NE + 255) / 256, 256, 0, stream>>>(eidx, flag, deg, NE);
    scan_kernel<<<1, 1024, 0, stream>>>(deg, row_ptr, fill_ctr, inv_deg, NN);
    fill_kernel<<<(NE + 255) / 256, 256, 0, stream>>>(eidx, flag, fill_ctr, csr_src, NE);

    const float* hin = x;
    float* bufs[2] = {h_a, h_b};
    for (int l = 0; l < NL; ++l) {
        float* hout = bufs[l & 1];
        agg_kernel<<<(NN * 64 + 255) / 256, 256, 0, stream>>>(hin, row_ptr, csr_src,
                                                              inv_deg, agg, NN);
        dim3 gb(D, 2);
        gemm_kernel<<<(NN + 7) / 8, gb, 0, stream>>>(hin, agg, w_ngh + (size_t)l * D * D,
                                                     w_self + (size_t)l * D * D,
                                                     bias + (size_t)l * D, hout, NN);
        dim3 sb(D, 4);
        bn_stats_kernel<<<256, sb, 0, stream>>>(hout, stats + (size_t)l * 2 * D, NN);
        bn_apply_kernel<<<(NN * (D / 4) + 255) / 256, 256, 0, stream>>>(
            hout, stats + (size_t)l * 2 * D, gamma + (size_t)l * D, beta + (size_t)l * D, NN);
        hin = hout;
    }
    clf_kernel<<<(NN + 255) / 256, 256, 0, stream>>>(hin, clf_w, clf_b, out, NN);
}

// Round 2
// 423.134 us; speedup vs baseline: 1.4532x; 1.4532x over previous
//
#include <hip/hip_runtime.h>

#define NN 50000
#define NE 800000
#define D 96
#define NL 3
#define NC 10
#define BN_EPS 1e-5f

typedef short bf16x8 __attribute__((ext_vector_type(8)));
typedef float f32x4 __attribute__((ext_vector_type(4)));

// ----------------------------- bf16 helpers ---------------------------------
__device__ __forceinline__ unsigned short f2b(float x) {
    unsigned int u = __float_as_uint(x);
    unsigned int r = (u + 0x7fffu + ((u >> 16) & 1u)) >> 16;
    return (unsigned short)r;
}
__device__ __forceinline__ float blo(unsigned int u) { return __uint_as_float(u << 16); }
__device__ __forceinline__ float bhi(unsigned int u) { return __uint_as_float(u & 0xffff0000u); }
__device__ __forceinline__ unsigned int pk2(float lo, float hi) {
    return ((unsigned int)f2b(lo)) | (((unsigned int)f2b(hi)) << 16);
}

// ---------------- edge index access (int32 vs int64 auto-detect) -------------
__device__ __forceinline__ int edge_at(const void* idx, int is64, long long pos) {
    if (is64) return (int)((const long long*)idx)[pos];
    return ((const int*)idx)[pos];
}

__global__ void detect_kernel(const int* __restrict__ words, int* __restrict__ flag) {
    __shared__ int any_nz;
    if (threadIdx.x == 0) any_nz = 0;
    __syncthreads();
    int v = words[2 * threadIdx.x + 1];
    if (v != 0) atomicOr(&any_nz, 1);
    __syncthreads();
    if (threadIdx.x == 0) *flag = any_nz ? 0 : 1;   // 1 => int64
}

__global__ void zero_kernel(int* __restrict__ deg, float* __restrict__ stats,
                            int ndeg, int nstats) {
    int i = blockIdx.x * blockDim.x + threadIdx.x;
    if (i < ndeg) deg[i] = 0;
    if (i < nstats) stats[i] = 0.f;
}

__global__ void deg_kernel(const void* __restrict__ idx, const int* __restrict__ flag,
                           int* __restrict__ deg, int E) {
    int e = blockIdx.x * blockDim.x + threadIdx.x;
    if (e >= E) return;
    int is64 = *flag;
    int d = edge_at(idx, is64, (long long)E + e);
    atomicAdd(&deg[d], 1);
}

// single-block exclusive scan (shfl-based), also writes fill counters + inv_deg
__global__ void scan_kernel(const int* __restrict__ deg, int* __restrict__ row_ptr,
                            int* __restrict__ fill_ctr, float* __restrict__ inv_deg, int n) {
    __shared__ int wsum[16];
    __shared__ int s_run;
    int tid = threadIdx.x;
    int lane = tid & 63;
    int w = tid >> 6;
    if (tid == 0) s_run = 0;
    __syncthreads();
    for (int base = 0; base < n; base += 1024) {
        int i = base + tid;
        int v = (i < n) ? deg[i] : 0;
        int x = v;
        #pragma unroll
        for (int off = 1; off < 64; off <<= 1) {
            int y = __shfl_up(x, off);
            if (lane >= off) x += y;
        }
        if (lane == 63) wsum[w] = x;
        __syncthreads();
        if (w == 0) {
            int t = (lane < 16) ? wsum[lane] : 0;
            #pragma unroll
            for (int off = 1; off < 16; off <<= 1) {
                int y = __shfl_up(t, off);
                if (lane >= off) t += y;
            }
            if (lane < 16) wsum[lane] = t;
        }
        __syncthreads();
        int run = s_run;
        int wofs = (w > 0) ? wsum[w - 1] : 0;
        int excl = run + wofs + x - v;
        if (i < n) {
            row_ptr[i] = excl;
            fill_ctr[i] = excl;
            inv_deg[i] = 1.0f / (float)(v > 0 ? v : 1);
        }
        __syncthreads();
        if (tid == 0) s_run = run + wsum[15];
        __syncthreads();
    }
    if (tid == 0) row_ptr[n] = s_run;
}

__global__ void fill_kernel(const void* __restrict__ idx, const int* __restrict__ flag,
                            int* __restrict__ fill_ctr, int* __restrict__ csr_src, int E) {
    int e = blockIdx.x * blockDim.x + threadIdx.x;
    if (e >= E) return;
    int is64 = *flag;
    int s = edge_at(idx, is64, e);
    int d = edge_at(idx, is64, (long long)E + e);
    int pos = atomicAdd(&fill_ctr[d], 1);
    csr_src[pos] = s;
}

// cast fp32 x -> bf16
__global__ void cast_kernel(const float* __restrict__ x, unsigned short* __restrict__ xb, int n4) {
    int i = blockIdx.x * blockDim.x + threadIdx.x;
    if (i >= n4) return;
    float4 v = ((const float4*)x)[i];
    ushort4 o;
    o.x = f2b(v.x); o.y = f2b(v.y); o.z = f2b(v.z); o.w = f2b(v.w);
    ((ushort4*)xb)[i] = o;
}

// W_T[l][col][k]: k<96 -> Wn[l][k][col], k>=96 -> Ws[l][k-96][col]  (bf16)
__global__ void prep_w_kernel(const float* __restrict__ wn, const float* __restrict__ ws,
                              unsigned short* __restrict__ wt) {
    int i = blockIdx.x * blockDim.x + threadIdx.x;
    if (i >= NL * D * 192) return;
    int k = i % 192;
    int col = (i / 192) % D;
    int l = i / (192 * D);
    float v = (k < D) ? wn[(size_t)l * D * D + k * D + col]
                      : ws[(size_t)l * D * D + (k - D) * D + col];
    wt[i] = f2b(v);
}

// one wave per dst node: mean-aggregate bf16 neighbor rows (lanes 0..47 active,
// each lane owns 2 features packed in one u32). 4 edges in flight.
__global__ void agg_kernel(const unsigned short* __restrict__ hb,
                           const int* __restrict__ row_ptr,
                           const int* __restrict__ csr_src,
                           const float* __restrict__ inv_deg,
                           unsigned short* __restrict__ aggb, int n) {
    int gid = blockIdx.x * blockDim.x + threadIdx.x;
    int node = gid >> 6;
    int lane = gid & 63;
    if (node >= n) return;
    int beg = row_ptr[node], end = row_ptr[node + 1];
    bool act = lane < 48;
    float a0 = 0.f, a1 = 0.f, b0 = 0.f, b1 = 0.f;
    float c0 = 0.f, c1 = 0.f, d0 = 0.f, d1 = 0.f;
    int e = beg;
    for (; e + 3 < end; e += 4) {
        int s0 = csr_src[e], s1 = csr_src[e + 1], s2 = csr_src[e + 2], s3 = csr_src[e + 3];
        if (act) {
            unsigned int u0 = *(const unsigned int*)(hb + (size_t)s0 * D + lane * 2);
            unsigned int u1 = *(const unsigned int*)(hb + (size_t)s1 * D + lane * 2);
            unsigned int u2 = *(const unsigned int*)(hb + (size_t)s2 * D + lane * 2);
            unsigned int u3 = *(const unsigned int*)(hb + (size_t)s3 * D + lane * 2);
            a0 += blo(u0); a1 += bhi(u0);
            b0 += blo(u1); b1 += bhi(u1);
            c0 += blo(u2); c1 += bhi(u2);
            d0 += blo(u3); d1 += bhi(u3);
        }
    }
    for (; e < end; ++e) {
        int s0 = csr_src[e];
        if (act) {
            unsigned int u0 = *(const unsigned int*)(hb + (size_t)s0 * D + lane * 2);
            a0 += blo(u0); a1 += bhi(u0);
        }
    }
    a0 = (a0 + b0) + (c0 + d0);
    a1 = (a1 + b1) + (c1 + d1);
    if (act) {
        float idg = inv_deg[node];
        *(unsigned int*)(aggb + (size_t)node * D + lane * 2) = pk2(a0 * idg, a1 * idg);
    }
}

// MFMA GEMM: hout[r][f] = sum_k [agg|h][r][k] * Wcat[k][f] + bias[f]  (bf16 in, bf16 out)
// + fused BN statistics (sum, sumsq per feature) from fp32 accumulators.
// 256 threads = 4 waves; wave owns 16 rows x 96 cols; K=192 (6 kfrags).
__global__ void __launch_bounds__(256) mfma_gemm_kernel(
        const unsigned short* __restrict__ aggb,   // [n][96] bf16 (k 0..95)
        const unsigned short* __restrict__ hb,     // [n][96] bf16 (k 96..191)
        const unsigned short* __restrict__ wt,     // [96 cols][192 k] bf16
        const float* __restrict__ bias,            // [96]
        unsigned short* __restrict__ hout,         // [n][96] bf16 (pre-BN)
        float* __restrict__ stats,                 // [192]: sums then sumsq
        int n) {
    __shared__ float red[4][192];
    int tid = threadIdx.x;
    int wave = tid >> 6;
    int lane = tid & 63;
    int m16 = lane & 15;
    int hi = lane >> 4;
    int rbase = blockIdx.x * 64 + wave * 16;

    // A fragments, read once from global (lane: row=m16, k = kk*32 + hi*8 + j)
    int arow = rbase + m16;
    int arowc = arow < n ? arow : n - 1;
    const unsigned short* ap = aggb + (size_t)arowc * D + hi * 8;
    const unsigned short* hp = hb + (size_t)arowc * D + hi * 8;
    bf16x8 A[6];
    #pragma unroll
    for (int kk = 0; kk < 3; ++kk) A[kk] = *reinterpret_cast<const bf16x8*>(ap + kk * 32);
    #pragma unroll
    for (int kk = 0; kk < 3; ++kk) A[3 + kk] = *reinterpret_cast<const bf16x8*>(hp + kk * 32);

    f32x4 acc[6];
    #pragma unroll
    for (int nn = 0; nn < 6; ++nn) acc[nn] = (f32x4){0.f, 0.f, 0.f, 0.f};

    #pragma unroll
    for (int nn = 0; nn < 6; ++nn) {
        int col = nn * 16 + m16;
        const unsigned short* wp = wt + (size_t)col * 192 + hi * 8;
        #pragma unroll
        for (int kk = 0; kk < 6; ++kk) {
            bf16x8 B = *reinterpret_cast<const bf16x8*>(wp + kk * 32);
            acc[nn] = __builtin_amdgcn_mfma_f32_16x16x32_bf16(A[kk], B, acc[nn], 0, 0, 0);
        }
    }

    // epilogue: bias, bf16 store (C layout: col = lane&15, row = hi*4 + reg),
    // BN partial sums
    #pragma unroll
    for (int nn = 0; nn < 6; ++nn) {
        int f = nn * 16 + m16;
        float bv = bias[f];
        float s = 0.f, q = 0.f;
        #pragma unroll
        for (int r = 0; r < 4; ++r) {
            int rrow = rbase + hi * 4 + r;
            float v = acc[nn][r] + bv;
            if (rrow < n) {
                hout[(size_t)rrow * D + f] = f2b(v);
                s += v;
                q += v * v;
            }
        }
        s += __shfl_xor(s, 16); q += __shfl_xor(q, 16);
        s += __shfl_xor(s, 32); q += __shfl_xor(q, 32);
        if (lane < 16) {
            red[wave][f] = s;
            red[wave][96 + f] = q;
        }
    }
    __syncthreads();
    if (tid < 192) {
        float t = red[0][tid] + red[1][tid] + red[2][tid] + red[3][tid];
        atomicAdd(&stats[tid], t);
    }
}

// stats -> per-feature scale/shift
__global__ void bn_finalize_kernel(const float* __restrict__ stats,
                                   const float* __restrict__ gamma,
                                   const float* __restrict__ beta,
                                   float* __restrict__ scsh, int n) {
    int f = threadIdx.x;
    if (f >= D) return;
    float inv_n = 1.0f / (float)n;
    float mu = stats[f] * inv_n;
    float var = stats[D + f] * inv_n - mu * mu;
    float sc = rsqrtf(var + BN_EPS) * gamma[f];
    scsh[f] = sc;
    scsh[D + f] = beta[f] - mu * sc;
}

// in-place bf16 BN + ReLU, 8 bf16 per thread
__global__ void bn_apply_kernel(unsigned short* __restrict__ h,
                                const float* __restrict__ scsh, int total8) {
    int i = blockIdx.x * blockDim.x + threadIdx.x;
    if (i >= total8) return;
    uint4 v = ((const uint4*)h)[i];
    int f0 = (i * 8) % D;
    unsigned int* pv = (unsigned int*)&v;
    #pragma unroll
    for (int j = 0; j < 4; ++j) {
        int f = f0 + 2 * j;
        float x0 = blo(pv[j]) * scsh[f] + scsh[D + f];
        float x1 = bhi(pv[j]) * scsh[f + 1] + scsh[D + f + 1];
        pv[j] = pk2(fmaxf(x0, 0.f), fmaxf(x1, 0.f));
    }
    ((uint4*)h)[i] = v;
}

__global__ void clf_kernel(const unsigned short* __restrict__ h, const float* __restrict__ W,
                           const float* __restrict__ b, float* __restrict__ out, int n) {
    __shared__ float sW[D * NC];
    __shared__ float sB[NC];
    int tid = threadIdx.x;
    for (int i = tid; i < D * NC; i += blockDim.x) sW[i] = W[i];
    if (tid < NC) sB[tid] = b[tid];
    __syncthreads();
    int node = blockIdx.x * blockDim.x + tid;
    if (node >= n) return;
    float acc[NC];
    #pragma unroll
    for (int c = 0; c < NC; ++c) acc[c] = sB[c];
    const uint4* row = (const uint4*)(h + (size_t)node * D);
    #pragma unroll
    for (int q4 = 0; q4 < D / 8; ++q4) {
        uint4 v = row[q4];
        unsigned int* pv = (unsigned int*)&v;
        #pragma unroll
        for (int j = 0; j < 4; ++j) {
            int k = q4 * 8 + j * 2;
            float x0 = blo(pv[j]);
            float x1 = bhi(pv[j]);
            #pragma unroll
            for (int c = 0; c < NC; ++c)
                acc[c] += x0 * sW[k * NC + c] + x1 * sW[(k + 1) * NC + c];
        }
    }
    float* orow = out + (size_t)node * NC;
    #pragma unroll
    for (int c = 0; c < NC; ++c) orow[c] = acc[c];
}

extern "C" void kernel_launch(void* const* d_in, const int* in_sizes, int n_in,
                              void* d_out, int out_size, void* d_ws, size_t ws_size,
                              hipStream_t stream) {
    const float* x      = (const float*)d_in[0];
    const void*  eidx   = d_in[1];
    const float* w_ngh  = (const float*)d_in[2];
    const float* w_self = (const float*)d_in[3];
    const float* bias   = (const float*)d_in[4];
    const float* gamma  = (const float*)d_in[5];
    const float* beta   = (const float*)d_in[6];
    const float* clf_w  = (const float*)d_in[7];
    const float* clf_b  = (const float*)d_in[8];
    float* out = (float*)d_out;

    char* ws = (char*)d_ws;
    size_t o = 0;
    auto alloc = [&](size_t bytes) -> void* {
        void* r = ws + o;
        o += (bytes + 255) & ~(size_t)255;
        return r;
    };
    int*   flag     = (int*)alloc(4);
    int*   deg      = (int*)alloc((size_t)NN * 4);
    int*   row_ptr  = (int*)alloc((size_t)(NN + 1) * 4);
    int*   fill_ctr = (int*)alloc((size_t)NN * 4);
    float* inv_deg  = (float*)alloc((size_t)NN * 4);
    int*   csr_src  = (int*)alloc((size_t)NE * 4);
    float* stats    = (float*)alloc((size_t)NL * 2 * D * 4);
    float* scsh     = (float*)alloc((size_t)NL * 2 * D * 4);
    unsigned short* wt   = (unsigned short*)alloc((size_t)NL * D * 192 * 2);
    unsigned short* xb   = (unsigned short*)alloc((size_t)NN * D * 2);
    unsigned short* aggb = (unsigned short*)alloc((size_t)NN * D * 2);
    unsigned short* hA   = (unsigned short*)alloc((size_t)NN * D * 2);
    unsigned short* hB   = (unsigned short*)alloc((size_t)NN * D * 2);

    detect_kernel<<<1, 256, 0, stream>>>((const int*)eidx, flag);
    zero_kernel<<<(NN + 255) / 256, 256, 0, stream>>>(deg, stats, NN, NL * 2 * D);
    deg_kernel<<<(NE + 255) / 256, 256, 0, stream>>>(eidx, flag, deg, NE);
    scan_kernel<<<1, 1024, 0, stream>>>(deg, row_ptr, fill_ctr, inv_deg, NN);
    fill_kernel<<<(NE + 255) / 256, 256, 0, stream>>>(eidx, flag, fill_ctr, csr_src, NE);
    cast_kernel<<<(NN * D / 4 + 255) / 256, 256, 0, stream>>>(x, xb, NN * D / 4);
    prep_w_kernel<<<(NL * D * 192 + 255) / 256, 256, 0, stream>>>(w_ngh, w_self, wt);

    const unsigned short* hin = xb;
    unsigned short* bufs[2] = {hA, hB};
    for (int l = 0; l < NL; ++l) {
        unsigned short* hout = bufs[l & 1];
        agg_kernel<<<(NN * 64 + 255) / 256, 256, 0, stream>>>(hin, row_ptr, csr_src,
                                                              inv_deg, aggb, NN);
        mfma_gemm_kernel<<<(NN + 63) / 64, 256, 0, stream>>>(
            aggb, hin, wt + (size_t)l * D * 192, bias + (size_t)l * D,
            hout, stats + (size_t)l * 2 * D, NN);
        bn_finalize_kernel<<<1, D, 0, stream>>>(stats + (size_t)l * 2 * D,
                                                gamma + (size_t)l * D, beta + (size_t)l * D,
                                                scsh + (size_t)l * 2 * D, NN);
        bn_apply_kernel<<<(NN * D / 8 + 255) / 256, 256, 0, stream>>>(
            hout, scsh + (size_t)l * 2 * D, NN * D / 8);
        hin = hout;
    }
    clf_kernel<<<(NN + 255) / 256, 256, 0, stream>>>(hin, clf_w, clf_b, out, NN);
}

// Round 3
// 289.159 us; speedup vs baseline: 2.1265x; 1.4633x over previous
//
#include <hip/hip_runtime.h>

#define NN 50000
#define NE 800000
#define D 96
#define NL 3
#define NC 10
#define BN_EPS 1e-5f
#define NB 196          // buckets of 256 dst nodes (dst >> 8)
#define CAP 6144        // max edges per bucket (mean 4082, +32 sigma)
#define EPB 2048        // edges per bin block

typedef short bf16x8 __attribute__((ext_vector_type(8)));
typedef float f32x4 __attribute__((ext_vector_type(4)));

// ----------------------------- bf16 helpers ---------------------------------
__device__ __forceinline__ unsigned short f2b(float x) {
    unsigned int u = __float_as_uint(x);
    unsigned int r = (u + 0x7fffu + ((u >> 16) & 1u)) >> 16;
    return (unsigned short)r;
}
__device__ __forceinline__ float blo(unsigned int u) { return __uint_as_float(u << 16); }
__device__ __forceinline__ float bhi(unsigned int u) { return __uint_as_float(u & 0xffff0000u); }
__device__ __forceinline__ unsigned int pk2(float lo, float hi) {
    return ((unsigned int)f2b(lo)) | (((unsigned int)f2b(hi)) << 16);
}

// ---------------- edge index access (int32 vs int64 auto-detect) -------------
__device__ __forceinline__ int edge_at(const void* idx, int is64, long long pos) {
    if (is64) return (int)((const long long*)idx)[pos];
    return ((const int*)idx)[pos];
}

__global__ void detect_kernel(const int* __restrict__ words, int* __restrict__ flag) {
    __shared__ int any_nz;
    if (threadIdx.x == 0) any_nz = 0;
    __syncthreads();
    int v = words[2 * threadIdx.x + 1];
    if (v != 0) atomicOr(&any_nz, 1);
    __syncthreads();
    if (threadIdx.x == 0) *flag = any_nz ? 0 : 1;   // 1 => int64
}

__global__ void zero2_kernel(int* __restrict__ cnt, float* __restrict__ stats) {
    int t = threadIdx.x;
    if (t < NB) cnt[t] = 0;
    if (t < NL * 2 * D) stats[t] = 0.f;
}

// bucket edges by dst>>8; write (src<<8)|(dst&255) into per-bucket regions
__global__ void __launch_bounds__(256) bin_kernel(
        const void* __restrict__ idx, const int* __restrict__ flag,
        int* __restrict__ cnt, unsigned int* __restrict__ binned, int E) {
    __shared__ int hist[256];
    __shared__ int gbase[256];
    __shared__ unsigned int pk[EPB];
    __shared__ unsigned char bkt[EPB];
    int t = threadIdx.x;
    int base = blockIdx.x * EPB;
    int is64 = *flag;
    hist[t] = 0;
    __syncthreads();
    #pragma unroll
    for (int j = 0; j < 8; ++j) {
        int i = t + j * 256;
        int e = base + i;
        if (e < E) {
            int s = edge_at(idx, is64, e);
            int d = edge_at(idx, is64, (long long)E + e);
            int b = d >> 8;
            bkt[i] = (unsigned char)b;
            pk[i] = ((unsigned int)s << 8) | (unsigned int)(d & 255);
            atomicAdd(&hist[b], 1);
        } else {
            bkt[i] = 0xFF;
        }
    }
    __syncthreads();
    int h = hist[t];
    int gb = 0;
    if (t < NB && h > 0) gb = atomicAdd(&cnt[t], h);
    gbase[t] = gb;
    hist[t] = 0;
    __syncthreads();
    #pragma unroll
    for (int j = 0; j < 8; ++j) {
        int i = t + j * 256;
        int b = bkt[i];
        if (b != 0xFF) {
            int loc = atomicAdd(&hist[b], 1);
            int pos = gbase[b] + loc;
            if (pos < CAP) binned[(size_t)b * CAP + pos] = pk[i];
        }
    }
}

// exclusive scan of 196 bucket counts (single block, 256 threads)
__global__ void bucket_scan_kernel(const int* __restrict__ cnt,
                                   int* __restrict__ bucket_base,
                                   int* __restrict__ row_ptr) {
    __shared__ int wsum[4];
    int t = threadIdx.x;
    int lane = t & 63, w = t >> 6;
    int v = (t < NB) ? cnt[t] : 0;
    int x = v;
    #pragma unroll
    for (int off = 1; off < 64; off <<= 1) {
        int y = __shfl_up(x, off);
        if (lane >= off) x += y;
    }
    if (lane == 63) wsum[w] = x;
    __syncthreads();
    if (t == 0) {
        int r = 0;
        #pragma unroll
        for (int i = 0; i < 4; ++i) { int tt = wsum[i]; wsum[i] = r; r += tt; }
    }
    __syncthreads();
    int excl = x - v + wsum[w];
    if (t < NB) bucket_base[t] = excl;
    if (t == 0) row_ptr[NN] = NE;
}

// per bucket: LDS degree count -> block scan -> row_ptr/inv_deg (coalesced),
// LDS-local CSR scatter, coalesced copy-out
__global__ void __launch_bounds__(256) fill_bucket_kernel(
        const unsigned int* __restrict__ binned, const int* __restrict__ cnt,
        const int* __restrict__ bucket_base, int* __restrict__ row_ptr,
        float* __restrict__ inv_deg, int* __restrict__ csr_src) {
    __shared__ int deg_l[256];
    __shared__ int wsum[4];
    __shared__ int lds_csr[CAP];
    int b = blockIdx.x;
    int t = threadIdx.x;
    int n0 = b << 8;
    int count = cnt[b]; if (count > CAP) count = CAP;
    int base = bucket_base[b];
    deg_l[t] = 0;
    __syncthreads();
    const unsigned int* reg = binned + (size_t)b * CAP;
    for (int i = t; i < count; i += 256) atomicAdd(&deg_l[reg[i] & 255], 1);
    __syncthreads();
    int v = deg_l[t];
    int lane = t & 63, w = t >> 6;
    int x = v;
    #pragma unroll
    for (int off = 1; off < 64; off <<= 1) {
        int y = __shfl_up(x, off);
        if (lane >= off) x += y;
    }
    if (lane == 63) wsum[w] = x;
    __syncthreads();
    if (t == 0) {
        int r = 0;
        #pragma unroll
        for (int i = 0; i < 4; ++i) { int tt = wsum[i]; wsum[i] = r; r += tt; }
    }
    __syncthreads();
    int excl = x - v + wsum[w];
    int node = n0 + t;
    if (node < NN) {
        row_ptr[node] = base + excl;
        inv_deg[node] = 1.0f / (float)(v > 0 ? v : 1);
    }
    deg_l[t] = excl;   // reuse as fill cursor (own slot only)
    __syncthreads();
    for (int i = t; i < count; i += 256) {
        unsigned int pk = reg[i];
        int loc = atomicAdd(&deg_l[pk & 255], 1);
        lds_csr[loc] = (int)(pk >> 8);
    }
    __syncthreads();
    for (int i = t; i < count; i += 256) csr_src[base + i] = lds_csr[i];
}

// cast fp32 x -> bf16
__global__ void cast_kernel(const float* __restrict__ x, unsigned short* __restrict__ xb, int n4) {
    int i = blockIdx.x * blockDim.x + threadIdx.x;
    if (i >= n4) return;
    float4 v = ((const float4*)x)[i];
    ushort4 o;
    o.x = f2b(v.x); o.y = f2b(v.y); o.z = f2b(v.z); o.w = f2b(v.w);
    ((ushort4*)xb)[i] = o;
}

// W_T[l][col][k]: k<96 -> Wn[l][k][col], k>=96 -> Ws[l][k-96][col]  (bf16)
__global__ void prep_w_kernel(const float* __restrict__ wn, const float* __restrict__ ws,
                              unsigned short* __restrict__ wt) {
    int i = blockIdx.x * blockDim.x + threadIdx.x;
    if (i >= NL * D * 192) return;
    int k = i % 192;
    int col = (i / 192) % D;
    int l = i / (192 * D);
    float v = (k < D) ? wn[(size_t)l * D * D + k * D + col]
                      : ws[(size_t)l * D * D + (k - D) * D + col];
    wt[i] = f2b(v);
}

// one wave per dst node: mean-aggregate bf16 neighbor rows (lanes 0..47 active,
// each lane owns 2 features packed in one u32). 8 edges in flight.
__global__ void agg_kernel(const unsigned short* __restrict__ hb,
                           const int* __restrict__ row_ptr,
                           const int* __restrict__ csr_src,
                           const float* __restrict__ inv_deg,
                           unsigned short* __restrict__ aggb, int n) {
    int gid = blockIdx.x * blockDim.x + threadIdx.x;
    int node = gid >> 6;
    int lane = gid & 63;
    if (node >= n) return;
    int beg = row_ptr[node], end = row_ptr[node + 1];
    bool act = lane < 48;
    float a0 = 0.f, a1 = 0.f, b0 = 0.f, b1 = 0.f;
    float c0 = 0.f, c1 = 0.f, d0 = 0.f, d1 = 0.f;
    int e = beg;
    for (; e + 7 < end; e += 8) {
        int s0 = csr_src[e],     s1 = csr_src[e + 1];
        int s2 = csr_src[e + 2], s3 = csr_src[e + 3];
        int s4 = csr_src[e + 4], s5 = csr_src[e + 5];
        int s6 = csr_src[e + 6], s7 = csr_src[e + 7];
        if (act) {
            unsigned int u0 = *(const unsigned int*)(hb + (size_t)s0 * D + lane * 2);
            unsigned int u1 = *(const unsigned int*)(hb + (size_t)s1 * D + lane * 2);
            unsigned int u2 = *(const unsigned int*)(hb + (size_t)s2 * D + lane * 2);
            unsigned int u3 = *(const unsigned int*)(hb + (size_t)s3 * D + lane * 2);
            unsigned int u4 = *(const unsigned int*)(hb + (size_t)s4 * D + lane * 2);
            unsigned int u5 = *(const unsigned int*)(hb + (size_t)s5 * D + lane * 2);
            unsigned int u6 = *(const unsigned int*)(hb + (size_t)s6 * D + lane * 2);
            unsigned int u7 = *(const unsigned int*)(hb + (size_t)s7 * D + lane * 2);
            a0 += blo(u0); a1 += bhi(u0); b0 += blo(u1); b1 += bhi(u1);
            c0 += blo(u2); c1 += bhi(u2); d0 += blo(u3); d1 += bhi(u3);
            a0 += blo(u4); a1 += bhi(u4); b0 += blo(u5); b1 += bhi(u5);
            c0 += blo(u6); c1 += bhi(u6); d0 += blo(u7); d1 += bhi(u7);
        }
    }
    for (; e + 3 < end; e += 4) {
        int s0 = csr_src[e],     s1 = csr_src[e + 1];
        int s2 = csr_src[e + 2], s3 = csr_src[e + 3];
        if (act) {
            unsigned int u0 = *(const unsigned int*)(hb + (size_t)s0 * D + lane * 2);
            unsigned int u1 = *(const unsigned int*)(hb + (size_t)s1 * D + lane * 2);
            unsigned int u2 = *(const unsigned int*)(hb + (size_t)s2 * D + lane * 2);
            unsigned int u3 = *(const unsigned int*)(hb + (size_t)s3 * D + lane * 2);
            a0 += blo(u0); a1 += bhi(u0); b0 += blo(u1); b1 += bhi(u1);
            c0 += blo(u2); c1 += bhi(u2); d0 += blo(u3); d1 += bhi(u3);
        }
    }
    for (; e < end; ++e) {
        int s0 = csr_src[e];
        if (act) {
            unsigned int u0 = *(const unsigned int*)(hb + (size_t)s0 * D + lane * 2);
            a0 += blo(u0); a1 += bhi(u0);
        }
    }
    a0 = (a0 + b0) + (c0 + d0);
    a1 = (a1 + b1) + (c1 + d1);
    if (act) {
        float idg = inv_deg[node];
        *(unsigned int*)(aggb + (size_t)node * D + lane * 2) = pk2(a0 * idg, a1 * idg);
    }
}

// MFMA GEMM: hout[r][f] = sum_k [agg|h][r][k] * Wcat[k][f] + bias[f]  (bf16 in/out)
// + fused BN statistics from fp32 accumulators.
__global__ void __launch_bounds__(256) mfma_gemm_kernel(
        const unsigned short* __restrict__ aggb,
        const unsigned short* __restrict__ hb,
        const unsigned short* __restrict__ wt,
        const float* __restrict__ bias,
        unsigned short* __restrict__ hout,
        float* __restrict__ stats,
        int n) {
    __shared__ float red[4][192];
    int tid = threadIdx.x;
    int wave = tid >> 6;
    int lane = tid & 63;
    int m16 = lane & 15;
    int hi = lane >> 4;
    int rbase = blockIdx.x * 64 + wave * 16;

    int arow = rbase + m16;
    int arowc = arow < n ? arow : n - 1;
    const unsigned short* ap = aggb + (size_t)arowc * D + hi * 8;
    const unsigned short* hp = hb + (size_t)arowc * D + hi * 8;
    bf16x8 A[6];
    #pragma unroll
    for (int kk = 0; kk < 3; ++kk) A[kk] = *reinterpret_cast<const bf16x8*>(ap + kk * 32);
    #pragma unroll
    for (int kk = 0; kk < 3; ++kk) A[3 + kk] = *reinterpret_cast<const bf16x8*>(hp + kk * 32);

    f32x4 acc[6];
    #pragma unroll
    for (int nn = 0; nn < 6; ++nn) acc[nn] = (f32x4){0.f, 0.f, 0.f, 0.f};

    #pragma unroll
    for (int nn = 0; nn < 6; ++nn) {
        int col = nn * 16 + m16;
        const unsigned short* wp = wt + (size_t)col * 192 + hi * 8;
        #pragma unroll
        for (int kk = 0; kk < 6; ++kk) {
            bf16x8 B = *reinterpret_cast<const bf16x8*>(wp + kk * 32);
            acc[nn] = __builtin_amdgcn_mfma_f32_16x16x32_bf16(A[kk], B, acc[nn], 0, 0, 0);
        }
    }

    #pragma unroll
    for (int nn = 0; nn < 6; ++nn) {
        int f = nn * 16 + m16;
        float bv = bias[f];
        float s = 0.f, q = 0.f;
        #pragma unroll
        for (int r = 0; r < 4; ++r) {
            int rrow = rbase + hi * 4 + r;
            float v = acc[nn][r] + bv;
            if (rrow < n) {
                hout[(size_t)rrow * D + f] = f2b(v);
                s += v;
                q += v * v;
            }
        }
        s += __shfl_xor(s, 16); q += __shfl_xor(q, 16);
        s += __shfl_xor(s, 32); q += __shfl_xor(q, 32);
        if (lane < 16) {
            red[wave][f] = s;
            red[wave][96 + f] = q;
        }
    }
    __syncthreads();
    if (tid < 192) {
        float t = red[0][tid] + red[1][tid] + red[2][tid] + red[3][tid];
        atomicAdd(&stats[tid], t);
    }
}

__global__ void bn_finalize_kernel(const float* __restrict__ stats,
                                   const float* __restrict__ gamma,
                                   const float* __restrict__ beta,
                                   float* __restrict__ scsh, int n) {
    int f = threadIdx.x;
    if (f >= D) return;
    float inv_n = 1.0f / (float)n;
    float mu = stats[f] * inv_n;
    float var = stats[D + f] * inv_n - mu * mu;
    float sc = rsqrtf(var + BN_EPS) * gamma[f];
    scsh[f] = sc;
    scsh[D + f] = beta[f] - mu * sc;
}

__global__ void bn_apply_kernel(unsigned short* __restrict__ h,
                                const float* __restrict__ scsh, int total8) {
    int i = blockIdx.x * blockDim.x + threadIdx.x;
    if (i >= total8) return;
    uint4 v = ((const uint4*)h)[i];
    int f0 = (i * 8) % D;
    unsigned int* pv = (unsigned int*)&v;
    #pragma unroll
    for (int j = 0; j < 4; ++j) {
        int f = f0 + 2 * j;
        float x0 = blo(pv[j]) * scsh[f] + scsh[D + f];
        float x1 = bhi(pv[j]) * scsh[f + 1] + scsh[D + f + 1];
        pv[j] = pk2(fmaxf(x0, 0.f), fmaxf(x1, 0.f));
    }
    ((uint4*)h)[i] = v;
}

__global__ void clf_kernel(const unsigned short* __restrict__ h, const float* __restrict__ W,
                           const float* __restrict__ b, float* __restrict__ out, int n) {
    __shared__ float sW[D * NC];
    __shared__ float sB[NC];
    int tid = threadIdx.x;
    for (int i = tid; i < D * NC; i += blockDim.x) sW[i] = W[i];
    if (tid < NC) sB[tid] = b[tid];
    __syncthreads();
    int node = blockIdx.x * blockDim.x + tid;
    if (node >= n) return;
    float acc[NC];
    #pragma unroll
    for (int c = 0; c < NC; ++c) acc[c] = sB[c];
    const uint4* row = (const uint4*)(h + (size_t)node * D);
    #pragma unroll
    for (int q4 = 0; q4 < D / 8; ++q4) {
        uint4 v = row[q4];
        unsigned int* pv = (unsigned int*)&v;
        #pragma unroll
        for (int j = 0; j < 4; ++j) {
            int k = q4 * 8 + j * 2;
            float x0 = blo(pv[j]);
            float x1 = bhi(pv[j]);
            #pragma unroll
            for (int c = 0; c < NC; ++c)
                acc[c] += x0 * sW[k * NC + c] + x1 * sW[(k + 1) * NC + c];
        }
    }
    float* orow = out + (size_t)node * NC;
    #pragma unroll
    for (int c = 0; c < NC; ++c) orow[c] = acc[c];
}

extern "C" void kernel_launch(void* const* d_in, const int* in_sizes, int n_in,
                              void* d_out, int out_size, void* d_ws, size_t ws_size,
                              hipStream_t stream) {
    const float* x      = (const float*)d_in[0];
    const void*  eidx   = d_in[1];
    const float* w_ngh  = (const float*)d_in[2];
    const float* w_self = (const float*)d_in[3];
    const float* bias   = (const float*)d_in[4];
    const float* gamma  = (const float*)d_in[5];
    const float* beta   = (const float*)d_in[6];
    const float* clf_w  = (const float*)d_in[7];
    const float* clf_b  = (const float*)d_in[8];
    float* out = (float*)d_out;

    char* ws = (char*)d_ws;
    size_t o = 0;
    auto alloc = [&](size_t bytes) -> void* {
        void* r = ws + o;
        o += (bytes + 255) & ~(size_t)255;
        return r;
    };
    int*   flag        = (int*)alloc(4);
    int*   row_ptr     = (int*)alloc((size_t)(NN + 1) * 4);
    float* inv_deg     = (float*)alloc((size_t)NN * 4);
    int*   csr_src     = (int*)alloc((size_t)NE * 4);
    float* stats       = (float*)alloc((size_t)NL * 2 * D * 4);
    float* scsh        = (float*)alloc((size_t)NL * 2 * D * 4);
    int*   cnt         = (int*)alloc((size_t)NB * 4);
    int*   bucket_base = (int*)alloc((size_t)NB * 4);
    unsigned short* wt   = (unsigned short*)alloc((size_t)NL * D * 192 * 2);
    unsigned short* xb   = (unsigned short*)alloc((size_t)NN * D * 2);
    unsigned short* aggb = (unsigned short*)alloc((size_t)NN * D * 2);
    unsigned short* hA   = (unsigned short*)alloc((size_t)NN * D * 2);
    unsigned short* hB   = (unsigned short*)alloc((size_t)NN * D * 2);
    // binned bucket regions alias hA (dead until layer-0 GEMM writes it)
    unsigned int* binned = (unsigned int*)hA;   // NB*CAP*4 = 4.8MB <= 9.6MB

    detect_kernel<<<1, 256, 0, stream>>>((const int*)eidx, flag);
    zero2_kernel<<<1, 1024, 0, stream>>>(cnt, stats);
    bin_kernel<<<(NE + EPB - 1) / EPB, 256, 0, stream>>>(eidx, flag, cnt, binned, NE);
    bucket_scan_kernel<<<1, 256, 0, stream>>>(cnt, bucket_base, row_ptr);
    fill_bucket_kernel<<<NB, 256, 0, stream>>>(binned, cnt, bucket_base,
                                               row_ptr, inv_deg, csr_src);
    cast_kernel<<<(NN * D / 4 + 255) / 256, 256, 0, stream>>>(x, xb, NN * D / 4);
    prep_w_kernel<<<(NL * D * 192 + 255) / 256, 256, 0, stream>>>(w_ngh, w_self, wt);

    const unsigned short* hin = xb;
    unsigned short* bufs[2] = {hA, hB};
    for (int l = 0; l < NL; ++l) {
        unsigned short* hout = bufs[l & 1];
        agg_kernel<<<(NN * 64 + 255) / 256, 256, 0, stream>>>(hin, row_ptr, csr_src,
                                                              inv_deg, aggb, NN);
        mfma_gemm_kernel<<<(NN + 63) / 64, 256, 0, stream>>>(
            aggb, hin, wt + (size_t)l * D * 192, bias + (size_t)l * D,
            hout, stats + (size_t)l * 2 * D, NN);
        bn_finalize_kernel<<<1, D, 0, stream>>>(stats + (size_t)l * 2 * D,
                                                gamma + (size_t)l * D, beta + (size_t)l * D,
                                                scsh + (size_t)l * 2 * D, NN);
        bn_apply_kernel<<<(NN * D / 8 + 255) / 256, 256, 0, stream>>>(
            hout, scsh + (size_t)l * 2 * D, NN * D / 8);
        hin = hout;
    }
    clf_kernel<<<(NN + 255) / 256, 256, 0, stream>>>(hin, clf_w, clf_b, out, NN);
}

// Round 4
// 272.543 us; speedup vs baseline: 2.2561x; 1.0610x over previous
//
#include <hip/hip_runtime.h>

#define NN 50000
#define NE 800000
#define D 96
#define NL 3
#define NC 10
#define BN_EPS 1e-5f
#define INV_N (1.0f / (float)NN)
#define NB 196          // buckets of 256 dst nodes (dst >> 8)
#define CAP 6144        // max edges per bucket (mean 4082, +32 sigma)
#define EPB 2048        // edges per bin block
#define CASTB ((NN * D / 4 + 255) / 256)       // 4688
#define PREPWB ((NL * D * 192 + 255) / 256)    // 216

typedef short bf16x8 __attribute__((ext_vector_type(8)));
typedef float f32x4 __attribute__((ext_vector_type(4)));

// ----------------------------- bf16 helpers ---------------------------------
__device__ __forceinline__ unsigned short f2b(float x) {
    unsigned int u = __float_as_uint(x);
    unsigned int r = (u + 0x7fffu + ((u >> 16) & 1u)) >> 16;
    return (unsigned short)r;
}
__device__ __forceinline__ float blo(unsigned int u) { return __uint_as_float(u << 16); }
__device__ __forceinline__ float bhi(unsigned int u) { return __uint_as_float(u & 0xffff0000u); }
__device__ __forceinline__ float b2f(short s) {
    return __uint_as_float(((unsigned int)(unsigned short)s) << 16);
}
__device__ __forceinline__ unsigned int pk2(float lo, float hi) {
    return ((unsigned int)f2b(lo)) | (((unsigned int)f2b(hi)) << 16);
}

// ---------------- edge index access (int32 vs int64 auto-detect) -------------
__device__ __forceinline__ int edge_at(const void* idx, int is64, long long pos) {
    if (is64) return (int)((const long long*)idx)[pos];
    return ((const int*)idx)[pos];
}

// merged front-end: cast x->bf16 | build W_T bf16 | detect int64 + zero cnt/stats
__global__ void __launch_bounds__(256) prep_kernel(
        const float* __restrict__ x, unsigned short* __restrict__ xb,
        const float* __restrict__ wn, const float* __restrict__ ws,
        unsigned short* __restrict__ wt,
        const int* __restrict__ words, int* __restrict__ flag,
        int* __restrict__ cnt, float* __restrict__ stats) {
    int b = blockIdx.x;
    int t = threadIdx.x;
    if (b < CASTB) {
        int i = b * 256 + t;
        if (i < NN * D / 4) {
            float4 v = ((const float4*)x)[i];
            ushort4 o;
            o.x = f2b(v.x); o.y = f2b(v.y); o.z = f2b(v.z); o.w = f2b(v.w);
            ((ushort4*)xb)[i] = o;
        }
        return;
    }
    if (b < CASTB + PREPWB) {
        int i = (b - CASTB) * 256 + t;
        if (i < NL * D * 192) {
            int k = i % 192;
            int col = (i / 192) % D;
            int l = i / (192 * D);
            float v = (k < D) ? wn[(size_t)l * D * D + k * D + col]
                              : ws[(size_t)l * D * D + (k - D) * D + col];
            wt[i] = f2b(v);
        }
        return;
    }
    // last block: detect + zeros
    __shared__ int any_nz;
    if (t == 0) any_nz = 0;
    __syncthreads();
    if (words[2 * t + 1] != 0) atomicOr(&any_nz, 1);
    __syncthreads();
    if (t == 0) *flag = any_nz ? 0 : 1;   // 1 => int64
    if (t < NB) cnt[t] = 0;
    for (int i = t; i < NL * 2 * D; i += 256) stats[i] = 0.f;
}

// bucket edges by dst>>8; write (src<<8)|(dst&255) into per-bucket regions
__global__ void __launch_bounds__(256) bin_kernel(
        const void* __restrict__ idx, const int* __restrict__ flag,
        int* __restrict__ cnt, unsigned int* __restrict__ binned, int E) {
    __shared__ int hist[256];
    __shared__ int gbase[256];
    __shared__ unsigned int pk[EPB];
    __shared__ unsigned char bkt[EPB];
    int t = threadIdx.x;
    int base = blockIdx.x * EPB;
    int is64 = *flag;
    hist[t] = 0;
    __syncthreads();
    #pragma unroll
    for (int j = 0; j < 8; ++j) {
        int i = t + j * 256;
        int e = base + i;
        if (e < E) {
            int s = edge_at(idx, is64, e);
            int d = edge_at(idx, is64, (long long)E + e);
            int b = d >> 8;
            bkt[i] = (unsigned char)b;
            pk[i] = ((unsigned int)s << 8) | (unsigned int)(d & 255);
            atomicAdd(&hist[b], 1);
        } else {
            bkt[i] = 0xFF;
        }
    }
    __syncthreads();
    int h = hist[t];
    int gb = 0;
    if (t < NB && h > 0) gb = atomicAdd(&cnt[t], h);
    gbase[t] = gb;
    hist[t] = 0;
    __syncthreads();
    #pragma unroll
    for (int j = 0; j < 8; ++j) {
        int i = t + j * 256;
        int b = bkt[i];
        if (b != 0xFF) {
            int loc = atomicAdd(&hist[b], 1);
            int pos = gbase[b] + loc;
            if (pos < CAP) binned[(size_t)b * CAP + pos] = pk[i];
        }
    }
}

// per bucket: in-block scan of all bucket counts -> base; LDS degree count ->
// scan -> row_ptr/inv_deg; LDS-local CSR scatter; coalesced copy-out
__global__ void __launch_bounds__(256) fill_bucket_kernel(
        const unsigned int* __restrict__ binned, const int* __restrict__ cnt,
        int* __restrict__ row_ptr, float* __restrict__ inv_deg,
        int* __restrict__ csr_src) {
    __shared__ int sexcl[256];
    __shared__ int deg_l[256];
    __shared__ int wsum[4];
    __shared__ int lds_csr[CAP];
    int b = blockIdx.x;
    int t = threadIdx.x;
    int lane = t & 63, w = t >> 6;
    // exclusive scan of cnt[0..NB) (every block does the same 256-wide scan)
    {
        int v = (t < NB) ? cnt[t] : 0;
        int x = v;
        #pragma unroll
        for (int off = 1; off < 64; off <<= 1) {
            int y = __shfl_up(x, off);
            if (lane >= off) x += y;
        }
        if (lane == 63) wsum[w] = x;
        __syncthreads();
        if (t == 0) {
            int r = 0;
            #pragma unroll
            for (int i = 0; i < 4; ++i) { int tt = wsum[i]; wsum[i] = r; r += tt; }
        }
        __syncthreads();
        sexcl[t] = x - v + wsum[w];
        __syncthreads();
    }
    int base = sexcl[b];
    int count = cnt[b]; if (count > CAP) count = CAP;
    int n0 = b << 8;
    deg_l[t] = 0;
    __syncthreads();
    const unsigned int* reg = binned + (size_t)b * CAP;
    for (int i = t; i < count; i += 256) atomicAdd(&deg_l[reg[i] & 255], 1);
    __syncthreads();
    int v = deg_l[t];
    int x = v;
    #pragma unroll
    for (int off = 1; off < 64; off <<= 1) {
        int y = __shfl_up(x, off);
        if (lane >= off) x += y;
    }
    if (lane == 63) wsum[w] = x;
    __syncthreads();
    if (t == 0) {
        int r = 0;
        #pragma unroll
        for (int i = 0; i < 4; ++i) { int tt = wsum[i]; wsum[i] = r; r += tt; }
    }
    __syncthreads();
    int excl = x - v + wsum[w];
    int node = n0 + t;
    if (node < NN) {
        row_ptr[node] = base + excl;
        inv_deg[node] = 1.0f / (float)(v > 0 ? v : 1);
    }
    if (b == 0 && t == 0) row_ptr[NN] = NE;
    deg_l[t] = excl;   // reuse as fill cursor
    __syncthreads();
    for (int i = t; i < count; i += 256) {
        unsigned int pkv = reg[i];
        int loc = atomicAdd(&deg_l[pkv & 255], 1);
        lds_csr[loc] = (int)(pkv >> 8);
    }
    __syncthreads();
    for (int i = t; i < count; i += 256) csr_src[base + i] = lds_csr[i];
}

// one wave per dst node; lazy BN+ReLU applied to gathered elements when use_bn.
__global__ void agg_kernel(const unsigned short* __restrict__ hb,
                           const int* __restrict__ row_ptr,
                           const int* __restrict__ csr_src,
                           const float* __restrict__ inv_deg,
                           unsigned short* __restrict__ aggb,
                           const float* __restrict__ stats_in,
                           const float* __restrict__ gamma_in,
                           const float* __restrict__ beta_in,
                           int use_bn, int n) {
    int gid = blockIdx.x * blockDim.x + threadIdx.x;
    int node = gid >> 6;
    int lane = gid & 63;
    if (node >= n) return;
    bool act = lane < 48;
    float sc0 = 1.f, sh0 = 0.f, sc1 = 1.f, sh1 = 0.f;
    float lo = use_bn ? 0.f : -3.0e38f;
    if (use_bn && act) {
        int f0 = lane * 2, f1 = f0 + 1;
        float mu0 = stats_in[f0] * INV_N;
        float va0 = stats_in[D + f0] * INV_N - mu0 * mu0;
        sc0 = rsqrtf(va0 + BN_EPS) * gamma_in[f0];
        sh0 = beta_in[f0] - mu0 * sc0;
        float mu1 = stats_in[f1] * INV_N;
        float va1 = stats_in[D + f1] * INV_N - mu1 * mu1;
        sc1 = rsqrtf(va1 + BN_EPS) * gamma_in[f1];
        sh1 = beta_in[f1] - mu1 * sc1;
    }
    int beg = row_ptr[node], end = row_ptr[node + 1];
    float a0 = 0.f, a1 = 0.f, b0 = 0.f, b1 = 0.f;
    float c0 = 0.f, c1 = 0.f, d0 = 0.f, d1 = 0.f;
    int e = beg;
#define ACC2(u, A0, A1) { A0 += fmaxf(fmaf(blo(u), sc0, sh0), lo); \
                          A1 += fmaxf(fmaf(bhi(u), sc1, sh1), lo); }
    for (; e + 7 < end; e += 8) {
        int s0 = csr_src[e],     s1 = csr_src[e + 1];
        int s2 = csr_src[e + 2], s3 = csr_src[e + 3];
        int s4 = csr_src[e + 4], s5 = csr_src[e + 5];
        int s6 = csr_src[e + 6], s7 = csr_src[e + 7];
        if (act) {
            unsigned int u0 = *(const unsigned int*)(hb + (size_t)s0 * D + lane * 2);
            unsigned int u1 = *(const unsigned int*)(hb + (size_t)s1 * D + lane * 2);
            unsigned int u2 = *(const unsigned int*)(hb + (size_t)s2 * D + lane * 2);
            unsigned int u3 = *(const unsigned int*)(hb + (size_t)s3 * D + lane * 2);
            unsigned int u4 = *(const unsigned int*)(hb + (size_t)s4 * D + lane * 2);
            unsigned int u5 = *(const unsigned int*)(hb + (size_t)s5 * D + lane * 2);
            unsigned int u6 = *(const unsigned int*)(hb + (size_t)s6 * D + lane * 2);
            unsigned int u7 = *(const unsigned int*)(hb + (size_t)s7 * D + lane * 2);
            ACC2(u0, a0, a1); ACC2(u1, b0, b1); ACC2(u2, c0, c1); ACC2(u3, d0, d1);
            ACC2(u4, a0, a1); ACC2(u5, b0, b1); ACC2(u6, c0, c1); ACC2(u7, d0, d1);
        }
    }
    for (; e + 3 < end; e += 4) {
        int s0 = csr_src[e],     s1 = csr_src[e + 1];
        int s2 = csr_src[e + 2], s3 = csr_src[e + 3];
        if (act) {
            unsigned int u0 = *(const unsigned int*)(hb + (size_t)s0 * D + lane * 2);
            unsigned int u1 = *(const unsigned int*)(hb + (size_t)s1 * D + lane * 2);
            unsigned int u2 = *(const unsigned int*)(hb + (size_t)s2 * D + lane * 2);
            unsigned int u3 = *(const unsigned int*)(hb + (size_t)s3 * D + lane * 2);
            ACC2(u0, a0, a1); ACC2(u1, b0, b1); ACC2(u2, c0, c1); ACC2(u3, d0, d1);
        }
    }
    for (; e < end; ++e) {
        int s0 = csr_src[e];
        if (act) {
            unsigned int u0 = *(const unsigned int*)(hb + (size_t)s0 * D + lane * 2);
            ACC2(u0, a0, a1);
        }
    }
#undef ACC2
    a0 = (a0 + b0) + (c0 + d0);
    a1 = (a1 + b1) + (c1 + d1);
    if (act) {
        float idg = inv_deg[node];
        *(unsigned int*)(aggb + (size_t)node * D + lane * 2) = pk2(a0 * idg, a1 * idg);
    }
}

// MFMA GEMM + fused BN stats. Self-term A fragments get lazy BN+ReLU when use_bn.
__global__ void __launch_bounds__(256) mfma_gemm_kernel(
        const unsigned short* __restrict__ aggb,
        const unsigned short* __restrict__ hb,
        const unsigned short* __restrict__ wt,
        const float* __restrict__ bias,
        unsigned short* __restrict__ hout,
        float* __restrict__ stats,
        const float* __restrict__ stats_in,
        const float* __restrict__ gamma_in,
        const float* __restrict__ beta_in,
        int use_bn, int n) {
    __shared__ float red[4][192];
    __shared__ float sSC[D];
    __shared__ float sSH[D];
    int tid = threadIdx.x;
    int wave = tid >> 6;
    int lane = tid & 63;
    int m16 = lane & 15;
    int hi = lane >> 4;
    int rbase = blockIdx.x * 64 + wave * 16;

    if (use_bn && tid < D) {
        float mu = stats_in[tid] * INV_N;
        float va = stats_in[D + tid] * INV_N - mu * mu;
        float sc = rsqrtf(va + BN_EPS) * gamma_in[tid];
        sSC[tid] = sc;
        sSH[tid] = beta_in[tid] - mu * sc;
    }
    __syncthreads();

    int arow = rbase + m16;
    int arowc = arow < n ? arow : n - 1;
    const unsigned short* ap = aggb + (size_t)arowc * D + hi * 8;
    const unsigned short* hp = hb + (size_t)arowc * D + hi * 8;
    bf16x8 A[6];
    #pragma unroll
    for (int kk = 0; kk < 3; ++kk) A[kk] = *reinterpret_cast<const bf16x8*>(ap + kk * 32);
    #pragma unroll
    for (int kk = 0; kk < 3; ++kk) {
        bf16x8 H = *reinterpret_cast<const bf16x8*>(hp + kk * 32);
        if (use_bn) {
            bf16x8 T;
            #pragma unroll
            for (int j = 0; j < 8; ++j) {
                int f = kk * 32 + hi * 8 + j;
                float v = fmaxf(fmaf(b2f(H[j]), sSC[f], sSH[f]), 0.f);
                T[j] = (short)f2b(v);
            }
            A[3 + kk] = T;
        } else {
            A[3 + kk] = H;
        }
    }

    f32x4 acc[6];
    #pragma unroll
    for (int nn = 0; nn < 6; ++nn) acc[nn] = (f32x4){0.f, 0.f, 0.f, 0.f};

    #pragma unroll
    for (int nn = 0; nn < 6; ++nn) {
        int col = nn * 16 + m16;
        const unsigned short* wp = wt + (size_t)col * 192 + hi * 8;
        #pragma unroll
        for (int kk = 0; kk < 6; ++kk) {
            bf16x8 B = *reinterpret_cast<const bf16x8*>(wp + kk * 32);
            acc[nn] = __builtin_amdgcn_mfma_f32_16x16x32_bf16(A[kk], B, acc[nn], 0, 0, 0);
        }
    }

    #pragma unroll
    for (int nn = 0; nn < 6; ++nn) {
        int f = nn * 16 + m16;
        float bv = bias[f];
        float s = 0.f, q = 0.f;
        #pragma unroll
        for (int r = 0; r < 4; ++r) {
            int rrow = rbase + hi * 4 + r;
            float v = acc[nn][r] + bv;
            if (rrow < n) {
                hout[(size_t)rrow * D + f] = f2b(v);
                s += v;
                q += v * v;
            }
        }
        s += __shfl_xor(s, 16); q += __shfl_xor(q, 16);
        s += __shfl_xor(s, 32); q += __shfl_xor(q, 32);
        if (lane < 16) {
            red[wave][f] = s;
            red[wave][96 + f] = q;
        }
    }
    __syncthreads();
    if (tid < 192) {
        float t = red[0][tid] + red[1][tid] + red[2][tid] + red[3][tid];
        atomicAdd(&stats[tid], t);
    }
}

// classifier with lazy BN+ReLU of the final layer
__global__ void clf_kernel(const unsigned short* __restrict__ h,
                           const float* __restrict__ W,
                           const float* __restrict__ b,
                           const float* __restrict__ stats_in,
                           const float* __restrict__ gamma_in,
                           const float* __restrict__ beta_in,
                           float* __restrict__ out, int n) {
    __shared__ float sW[D * NC];
    __shared__ float sB[NC];
    __shared__ float sSC[D];
    __shared__ float sSH[D];
    int tid = threadIdx.x;
    for (int i = tid; i < D * NC; i += blockDim.x) sW[i] = W[i];
    if (tid < NC) sB[tid] = b[tid];
    if (tid < D) {
        float mu = stats_in[tid] * INV_N;
        float va = stats_in[D + tid] * INV_N - mu * mu;
        float sc = rsqrtf(va + BN_EPS) * gamma_in[tid];
        sSC[tid] = sc;
        sSH[tid] = beta_in[tid] - mu * sc;
    }
    __syncthreads();
    int node = blockIdx.x * blockDim.x + tid;
    if (node >= n) return;
    float acc[NC];
    #pragma unroll
    for (int c = 0; c < NC; ++c) acc[c] = sB[c];
    const uint4* row = (const uint4*)(h + (size_t)node * D);
    #pragma unroll
    for (int q4 = 0; q4 < D / 8; ++q4) {
        uint4 v = row[q4];
        unsigned int* pv = (unsigned int*)&v;
        #pragma unroll
        for (int j = 0; j < 4; ++j) {
            int k = q4 * 8 + j * 2;
            float x0 = fmaxf(fmaf(blo(pv[j]), sSC[k], sSH[k]), 0.f);
            float x1 = fmaxf(fmaf(bhi(pv[j]), sSC[k + 1], sSH[k + 1]), 0.f);
            #pragma unroll
            for (int c = 0; c < NC; ++c)
                acc[c] += x0 * sW[k * NC + c] + x1 * sW[(k + 1) * NC + c];
        }
    }
    float* orow = out + (size_t)node * NC;
    #pragma unroll
    for (int c = 0; c < NC; ++c) orow[c] = acc[c];
}

extern "C" void kernel_launch(void* const* d_in, const int* in_sizes, int n_in,
                              void* d_out, int out_size, void* d_ws, size_t ws_size,
                              hipStream_t stream) {
    const float* x      = (const float*)d_in[0];
    const void*  eidx   = d_in[1];
    const float* w_ngh  = (const float*)d_in[2];
    const float* w_self = (const float*)d_in[3];
    const float* bias   = (const float*)d_in[4];
    const float* gamma  = (const float*)d_in[5];
    const float* beta   = (const float*)d_in[6];
    const float* clf_w  = (const float*)d_in[7];
    const float* clf_b  = (const float*)d_in[8];
    float* out = (float*)d_out;

    char* ws = (char*)d_ws;
    size_t o = 0;
    auto alloc = [&](size_t bytes) -> void* {
        void* r = ws + o;
        o += (bytes + 255) & ~(size_t)255;
        return r;
    };
    int*   flag    = (int*)alloc(4);
    int*   row_ptr = (int*)alloc((size_t)(NN + 1) * 4);
    float* inv_deg = (float*)alloc((size_t)NN * 4);
    int*   csr_src = (int*)alloc((size_t)NE * 4);
    float* stats   = (float*)alloc((size_t)NL * 2 * D * 4);
    int*   cnt     = (int*)alloc((size_t)NB * 4);
    unsigned short* wt   = (unsigned short*)alloc((size_t)NL * D * 192 * 2);
    unsigned short* xb   = (unsigned short*)alloc((size_t)NN * D * 2);
    unsigned short* aggb = (unsigned short*)alloc((size_t)NN * D * 2);
    unsigned short* hA   = (unsigned short*)alloc((size_t)NN * D * 2);
    unsigned short* hB   = (unsigned short*)alloc((size_t)NN * D * 2);
    // binned bucket regions alias hA (dead until layer-0 GEMM writes it)
    unsigned int* binned = (unsigned int*)hA;   // NB*CAP*4 = 4.8MB <= 9.6MB

    prep_kernel<<<CASTB + PREPWB + 1, 256, 0, stream>>>(
        x, xb, w_ngh, w_self, wt, (const int*)eidx, flag, cnt, stats);
    bin_kernel<<<(NE + EPB - 1) / EPB, 256, 0, stream>>>(eidx, flag, cnt, binned, NE);
    fill_bucket_kernel<<<NB, 256, 0, stream>>>(binned, cnt, row_ptr, inv_deg, csr_src);

    const unsigned short* hin = xb;
    unsigned short* bufs[2] = {hA, hB};
    for (int l = 0; l < NL; ++l) {
        unsigned short* hout = bufs[l & 1];
        const float* st_in = stats + (size_t)(l - 1) * 2 * D;
        const float* g_in  = gamma + (size_t)(l - 1) * D;
        const float* b_in  = beta + (size_t)(l - 1) * D;
        int use_bn = (l > 0) ? 1 : 0;
        if (!use_bn) { st_in = stats; g_in = gamma; b_in = beta; }  // unread
        agg_kernel<<<(NN * 64 + 255) / 256, 256, 0, stream>>>(
            hin, row_ptr, csr_src, inv_deg, aggb, st_in, g_in, b_in, use_bn, NN);
        mfma_gemm_kernel<<<(NN + 63) / 64, 256, 0, stream>>>(
            aggb, hin, wt + (size_t)l * D * 192, bias + (size_t)l * D,
            hout, stats + (size_t)l * 2 * D, st_in, g_in, b_in, use_bn, NN);
        hin = hout;
    }
    clf_kernel<<<(NN + 255) / 256, 256, 0, stream>>>(
        hin, clf_w, clf_b, stats + (size_t)2 * 2 * D, gamma + (size_t)2 * D,
        beta + (size_t)2 * D, out, NN);
}

// Round 5
// 271.114 us; speedup vs baseline: 2.2680x; 1.0053x over previous
//
#include <hip/hip_runtime.h>

#define NN 50000
#define NE 800000
#define D 96
#define NL 3
#define NC 10
#define BN_EPS 1e-5f
#define INV_N (1.0f / (float)NN)
#define NB 196          // buckets of 256 dst nodes (dst >> 8)
#define CAP 6144        // max edges per bucket (mean 4082, +32 sigma)
#define EPB 2048        // edges per bin block
#define NREP 16         // stats replication factor (atomic contention)
#define WPAD 200        // padded wt row stride (shorts); 400B keeps 16B alignment
#define CASTB ((NN * D / 4 + 255) / 256)       // 4688
#define PREPWB ((NL * D * 192 + 255) / 256)    // 216

typedef short bf16x8 __attribute__((ext_vector_type(8)));
typedef unsigned short u16x8 __attribute__((ext_vector_type(8)));
typedef float f32x4 __attribute__((ext_vector_type(4)));

// ----------------------------- bf16 helpers ---------------------------------
__device__ __forceinline__ unsigned short f2b(float x) {
    unsigned int u = __float_as_uint(x);
    unsigned int r = (u + 0x7fffu + ((u >> 16) & 1u)) >> 16;
    return (unsigned short)r;
}
__device__ __forceinline__ float blo(unsigned int u) { return __uint_as_float(u << 16); }
__device__ __forceinline__ float bhi(unsigned int u) { return __uint_as_float(u & 0xffff0000u); }
__device__ __forceinline__ float b2f(short s) {
    return __uint_as_float(((unsigned int)(unsigned short)s) << 16);
}
__device__ __forceinline__ unsigned int pk2(float lo, float hi) {
    return ((unsigned int)f2b(lo)) | (((unsigned int)f2b(hi)) << 16);
}

// ---------------- edge index access (int32 vs int64 auto-detect) -------------
__device__ __forceinline__ int edge_at(const void* idx, int is64, long long pos) {
    if (is64) return (int)((const long long*)idx)[pos];
    return ((const int*)idx)[pos];
}

// merged front-end: cast x->bf16 | build padded W_T bf16 | detect + zero
__global__ void __launch_bounds__(256) prep_kernel(
        const float* __restrict__ x, unsigned short* __restrict__ xb,
        const float* __restrict__ wn, const float* __restrict__ ws,
        unsigned short* __restrict__ wt,
        const int* __restrict__ words, int* __restrict__ flag,
        int* __restrict__ cnt, float* __restrict__ stats) {
    int b = blockIdx.x;
    int t = threadIdx.x;
    if (b < CASTB) {
        int i = b * 256 + t;
        if (i < NN * D / 4) {
            float4 v = ((const float4*)x)[i];
            ushort4 o;
            o.x = f2b(v.x); o.y = f2b(v.y); o.z = f2b(v.z); o.w = f2b(v.w);
            ((ushort4*)xb)[i] = o;
        }
        return;
    }
    if (b < CASTB + PREPWB) {
        int i = (b - CASTB) * 256 + t;
        if (i < NL * D * 192) {
            int k = i % 192;
            int col = (i / 192) % D;
            int l = i / (192 * D);
            float v = (k < D) ? wn[(size_t)l * D * D + k * D + col]
                              : ws[(size_t)l * D * D + (k - D) * D + col];
            wt[((size_t)l * D + col) * WPAD + k] = f2b(v);
        }
        return;
    }
    // last block: detect + zeros
    __shared__ int any_nz;
    if (t == 0) any_nz = 0;
    __syncthreads();
    if (words[2 * t + 1] != 0) atomicOr(&any_nz, 1);
    __syncthreads();
    if (t == 0) *flag = any_nz ? 0 : 1;   // 1 => int64
    if (t < NB) cnt[t] = 0;
    for (int i = t; i < NL * NREP * 2 * D; i += 256) stats[i] = 0.f;
}

// bucket edges by dst>>8; write (src<<8)|(dst&255) into per-bucket regions
__global__ void __launch_bounds__(256) bin_kernel(
        const void* __restrict__ idx, const int* __restrict__ flag,
        int* __restrict__ cnt, unsigned int* __restrict__ binned, int E) {
    __shared__ int hist[256];
    __shared__ int gbase[256];
    __shared__ unsigned int pk[EPB];
    __shared__ unsigned char bkt[EPB];
    int t = threadIdx.x;
    int base = blockIdx.x * EPB;
    int is64 = *flag;
    hist[t] = 0;
    __syncthreads();
    #pragma unroll
    for (int j = 0; j < 8; ++j) {
        int i = t + j * 256;
        int e = base + i;
        if (e < E) {
            int s = edge_at(idx, is64, e);
            int d = edge_at(idx, is64, (long long)E + e);
            int b = d >> 8;
            bkt[i] = (unsigned char)b;
            pk[i] = ((unsigned int)s << 8) | (unsigned int)(d & 255);
            atomicAdd(&hist[b], 1);
        } else {
            bkt[i] = 0xFF;
        }
    }
    __syncthreads();
    int h = hist[t];
    int gb = 0;
    if (t < NB && h > 0) gb = atomicAdd(&cnt[t], h);
    gbase[t] = gb;
    hist[t] = 0;
    __syncthreads();
    #pragma unroll
    for (int j = 0; j < 8; ++j) {
        int i = t + j * 256;
        int b = bkt[i];
        if (b != 0xFF) {
            int loc = atomicAdd(&hist[b], 1);
            int pos = gbase[b] + loc;
            if (pos < CAP) binned[(size_t)b * CAP + pos] = pk[i];
        }
    }
}

// per bucket: in-block scan of bucket counts -> base; LDS degree count ->
// scan -> row_ptr/inv_deg; LDS-local CSR scatter; coalesced copy-out
__global__ void __launch_bounds__(256) fill_bucket_kernel(
        const unsigned int* __restrict__ binned, const int* __restrict__ cnt,
        int* __restrict__ row_ptr, float* __restrict__ inv_deg,
        int* __restrict__ csr_src) {
    __shared__ int sexcl[256];
    __shared__ int deg_l[256];
    __shared__ int wsum[4];
    __shared__ int lds_csr[CAP];
    int b = blockIdx.x;
    int t = threadIdx.x;
    int lane = t & 63, w = t >> 6;
    {
        int v = (t < NB) ? cnt[t] : 0;
        int x = v;
        #pragma unroll
        for (int off = 1; off < 64; off <<= 1) {
            int y = __shfl_up(x, off);
            if (lane >= off) x += y;
        }
        if (lane == 63) wsum[w] = x;
        __syncthreads();
        if (t == 0) {
            int r = 0;
            #pragma unroll
            for (int i = 0; i < 4; ++i) { int tt = wsum[i]; wsum[i] = r; r += tt; }
        }
        __syncthreads();
        sexcl[t] = x - v + wsum[w];
        __syncthreads();
    }
    int base = sexcl[b];
    int count = cnt[b]; if (count > CAP) count = CAP;
    int n0 = b << 8;
    deg_l[t] = 0;
    __syncthreads();
    const unsigned int* reg = binned + (size_t)b * CAP;
    for (int i = t; i < count; i += 256) atomicAdd(&deg_l[reg[i] & 255], 1);
    __syncthreads();
    int v = deg_l[t];
    int x = v;
    #pragma unroll
    for (int off = 1; off < 64; off <<= 1) {
        int y = __shfl_up(x, off);
        if (lane >= off) x += y;
    }
    if (lane == 63) wsum[w] = x;
    __syncthreads();
    if (t == 0) {
        int r = 0;
        #pragma unroll
        for (int i = 0; i < 4; ++i) { int tt = wsum[i]; wsum[i] = r; r += tt; }
    }
    __syncthreads();
    int excl = x - v + wsum[w];
    int node = n0 + t;
    if (node < NN) {
        row_ptr[node] = base + excl;
        inv_deg[node] = 1.0f / (float)(v > 0 ? v : 1);
    }
    if (b == 0 && t == 0) row_ptr[NN] = NE;
    deg_l[t] = excl;   // reuse as fill cursor
    __syncthreads();
    for (int i = t; i < count; i += 256) {
        unsigned int pkv = reg[i];
        int loc = atomicAdd(&deg_l[pkv & 255], 1);
        lds_csr[loc] = (int)(pkv >> 8);
    }
    __syncthreads();
    for (int i = t; i < count; i += 256) csr_src[base + i] = lds_csr[i];
}

// one wave per dst node; lazy BN+ReLU applied to gathered elements when use_bn.
__global__ void agg_kernel(const unsigned short* __restrict__ hb,
                           const int* __restrict__ row_ptr,
                           const int* __restrict__ csr_src,
                           const float* __restrict__ inv_deg,
                           unsigned short* __restrict__ aggb,
                           const float* __restrict__ stats_in,
                           const float* __restrict__ gamma_in,
                           const float* __restrict__ beta_in,
                           int use_bn, int n) {
    int gid = blockIdx.x * blockDim.x + threadIdx.x;
    int node = gid >> 6;
    int lane = gid & 63;
    if (node >= n) return;
    bool act = lane < 48;
    float sc0 = 1.f, sh0 = 0.f, sc1 = 1.f, sh1 = 0.f;
    float lo = use_bn ? 0.f : -3.0e38f;
    if (use_bn && act) {
        int f0 = lane * 2, f1 = f0 + 1;
        float s0 = 0.f, q0 = 0.f, s1 = 0.f, q1 = 0.f;
        #pragma unroll 4
        for (int r = 0; r < NREP; ++r) {
            const float* sp = stats_in + r * 2 * D;
            s0 += sp[f0]; q0 += sp[D + f0];
            s1 += sp[f1]; q1 += sp[D + f1];
        }
        float mu0 = s0 * INV_N;
        float va0 = q0 * INV_N - mu0 * mu0;
        sc0 = rsqrtf(va0 + BN_EPS) * gamma_in[f0];
        sh0 = beta_in[f0] - mu0 * sc0;
        float mu1 = s1 * INV_N;
        float va1 = q1 * INV_N - mu1 * mu1;
        sc1 = rsqrtf(va1 + BN_EPS) * gamma_in[f1];
        sh1 = beta_in[f1] - mu1 * sc1;
    }
    int beg = row_ptr[node], end = row_ptr[node + 1];
    float a0 = 0.f, a1 = 0.f, b0 = 0.f, b1 = 0.f;
    float c0 = 0.f, c1 = 0.f, d0 = 0.f, d1 = 0.f;
    int e = beg;
#define ACC2(u, A0, A1) { A0 += fmaxf(fmaf(blo(u), sc0, sh0), lo); \
                          A1 += fmaxf(fmaf(bhi(u), sc1, sh1), lo); }
    for (; e + 7 < end; e += 8) {
        int s0 = csr_src[e],     s1 = csr_src[e + 1];
        int s2 = csr_src[e + 2], s3 = csr_src[e + 3];
        int s4 = csr_src[e + 4], s5 = csr_src[e + 5];
        int s6 = csr_src[e + 6], s7 = csr_src[e + 7];
        if (act) {
            unsigned int u0 = *(const unsigned int*)(hb + (size_t)s0 * D + lane * 2);
            unsigned int u1 = *(const unsigned int*)(hb + (size_t)s1 * D + lane * 2);
            unsigned int u2 = *(const unsigned int*)(hb + (size_t)s2 * D + lane * 2);
            unsigned int u3 = *(const unsigned int*)(hb + (size_t)s3 * D + lane * 2);
            unsigned int u4 = *(const unsigned int*)(hb + (size_t)s4 * D + lane * 2);
            unsigned int u5 = *(const unsigned int*)(hb + (size_t)s5 * D + lane * 2);
            unsigned int u6 = *(const unsigned int*)(hb + (size_t)s6 * D + lane * 2);
            unsigned int u7 = *(const unsigned int*)(hb + (size_t)s7 * D + lane * 2);
            ACC2(u0, a0, a1); ACC2(u1, b0, b1); ACC2(u2, c0, c1); ACC2(u3, d0, d1);
            ACC2(u4, a0, a1); ACC2(u5, b0, b1); ACC2(u6, c0, c1); ACC2(u7, d0, d1);
        }
    }
    for (; e + 3 < end; e += 4) {
        int s0 = csr_src[e],     s1 = csr_src[e + 1];
        int s2 = csr_src[e + 2], s3 = csr_src[e + 3];
        if (act) {
            unsigned int u0 = *(const unsigned int*)(hb + (size_t)s0 * D + lane * 2);
            unsigned int u1 = *(const unsigned int*)(hb + (size_t)s1 * D + lane * 2);
            unsigned int u2 = *(const unsigned int*)(hb + (size_t)s2 * D + lane * 2);
            unsigned int u3 = *(const unsigned int*)(hb + (size_t)s3 * D + lane * 2);
            ACC2(u0, a0, a1); ACC2(u1, b0, b1); ACC2(u2, c0, c1); ACC2(u3, d0, d1);
        }
    }
    for (; e < end; ++e) {
        int s0 = csr_src[e];
        if (act) {
            unsigned int u0 = *(const unsigned int*)(hb + (size_t)s0 * D + lane * 2);
            ACC2(u0, a0, a1);
        }
    }
#undef ACC2
    a0 = (a0 + b0) + (c0 + d0);
    a1 = (a1 + b1) + (c1 + d1);
    if (act) {
        float idg = inv_deg[node];
        *(unsigned int*)(aggb + (size_t)node * D + lane * 2) = pk2(a0 * idg, a1 * idg);
    }
}

// MFMA GEMM + fused BN stats. B operands LDS-staged; stats atomics replicated.
__global__ void __launch_bounds__(256) mfma_gemm_kernel(
        const unsigned short* __restrict__ aggb,
        const unsigned short* __restrict__ hb,
        const unsigned short* __restrict__ wt,    // [96][WPAD] padded, this layer
        const float* __restrict__ bias,
        unsigned short* __restrict__ hout,
        float* __restrict__ stats,                // this layer, NREP replicas
        const float* __restrict__ stats_in,       // prev layer, NREP replicas
        const float* __restrict__ gamma_in,
        const float* __restrict__ beta_in,
        int use_bn, int n) {
    __shared__ float red[4][192];
    __shared__ float sSC[D];
    __shared__ float sSH[D];
    __shared__ unsigned short sW[D][WPAD];   // 38.4 KB
    int tid = threadIdx.x;
    int wave = tid >> 6;
    int lane = tid & 63;
    int m16 = lane & 15;
    int hi = lane >> 4;
    int rbase = blockIdx.x * 64 + wave * 16;

    // 1) A-fragment global loads first (12 independent b128s)
    int arow = rbase + m16;
    int arowc = arow < n ? arow : n - 1;
    const unsigned short* ap = aggb + (size_t)arowc * D + hi * 8;
    const unsigned short* hp = hb + (size_t)arowc * D + hi * 8;
    bf16x8 A[6], H[3];
    #pragma unroll
    for (int kk = 0; kk < 3; ++kk) A[kk] = *reinterpret_cast<const bf16x8*>(ap + kk * 32);
    #pragma unroll
    for (int kk = 0; kk < 3; ++kk) H[kk] = *reinterpret_cast<const bf16x8*>(hp + kk * 32);

    // 2) cooperative wt staging: 96 cols x 24 chunks of 16B, coalesced
    #pragma unroll
    for (int c = 0; c < 9; ++c) {
        int i = tid + c * 256;
        int col = i / 24, seg = i % 24;
        *reinterpret_cast<u16x8*>(&sW[col][seg * 8]) =
            *reinterpret_cast<const u16x8*>(wt + (size_t)col * WPAD + seg * 8);
    }

    // 3) BN scale/shift of previous layer (replica-summed)
    if (use_bn && tid < D) {
        float s = 0.f, q = 0.f;
        #pragma unroll 4
        for (int r = 0; r < NREP; ++r) {
            s += stats_in[r * 2 * D + tid];
            q += stats_in[r * 2 * D + D + tid];
        }
        float mu = s * INV_N;
        float va = q * INV_N - mu * mu;
        float sc = rsqrtf(va + BN_EPS) * gamma_in[tid];
        sSC[tid] = sc;
        sSH[tid] = beta_in[tid] - mu * sc;
    }
    __syncthreads();

    // 4) lazy BN+ReLU on self-term fragments
    #pragma unroll
    for (int kk = 0; kk < 3; ++kk) {
        if (use_bn) {
            bf16x8 T;
            #pragma unroll
            for (int j = 0; j < 8; ++j) {
                int f = kk * 32 + hi * 8 + j;
                float v = fmaxf(fmaf(b2f(H[kk][j]), sSC[f], sSH[f]), 0.f);
                T[j] = (short)f2b(v);
            }
            A[3 + kk] = T;
        } else {
            A[3 + kk] = H[kk];
        }
    }

    // 5) MFMA loop, B from LDS
    f32x4 acc[6];
    #pragma unroll
    for (int nn = 0; nn < 6; ++nn) acc[nn] = (f32x4){0.f, 0.f, 0.f, 0.f};
    #pragma unroll
    for (int nn = 0; nn < 6; ++nn) {
        int col = nn * 16 + m16;
        #pragma unroll
        for (int kk = 0; kk < 6; ++kk) {
            bf16x8 B = *reinterpret_cast<const bf16x8*>(&sW[col][kk * 32 + hi * 8]);
            acc[nn] = __builtin_amdgcn_mfma_f32_16x16x32_bf16(A[kk], B, acc[nn], 0, 0, 0);
        }
    }

    // 6) epilogue: bias, bf16 store, BN partial sums -> replicated atomics
    #pragma unroll
    for (int nn = 0; nn < 6; ++nn) {
        int f = nn * 16 + m16;
        float bv = bias[f];
        float s = 0.f, q = 0.f;
        #pragma unroll
        for (int r = 0; r < 4; ++r) {
            int rrow = rbase + hi * 4 + r;
            float v = acc[nn][r] + bv;
            if (rrow < n) {
                hout[(size_t)rrow * D + f] = f2b(v);
                s += v;
                q += v * v;
            }
        }
        s += __shfl_xor(s, 16); q += __shfl_xor(q, 16);
        s += __shfl_xor(s, 32); q += __shfl_xor(q, 32);
        if (lane < 16) {
            red[wave][f] = s;
            red[wave][96 + f] = q;
        }
    }
    __syncthreads();
    if (tid < 192) {
        float t = red[0][tid] + red[1][tid] + red[2][tid] + red[3][tid];
        atomicAdd(&stats[(blockIdx.x & (NREP - 1)) * 2 * D + tid], t);
    }
}

// classifier with lazy BN+ReLU of the final layer
__global__ void clf_kernel(const unsigned short* __restrict__ h,
                           const float* __restrict__ W,
                           const float* __restrict__ b,
                           const float* __restrict__ stats_in,
                           const float* __restrict__ gamma_in,
                           const float* __restrict__ beta_in,
                           float* __restrict__ out, int n) {
    __shared__ float sW[D * NC];
    __shared__ float sB[NC];
    __shared__ float sSC[D];
    __shared__ float sSH[D];
    int tid = threadIdx.x;
    for (int i = tid; i < D * NC; i += blockDim.x) sW[i] = W[i];
    if (tid < NC) sB[tid] = b[tid];
    if (tid < D) {
        float s = 0.f, q = 0.f;
        #pragma unroll 4
        for (int r = 0; r < NREP; ++r) {
            s += stats_in[r * 2 * D + tid];
            q += stats_in[r * 2 * D + D + tid];
        }
        float mu = s * INV_N;
        float va = q * INV_N - mu * mu;
        float sc = rsqrtf(va + BN_EPS) * gamma_in[tid];
        sSC[tid] = sc;
        sSH[tid] = beta_in[tid] - mu * sc;
    }
    __syncthreads();
    int node = blockIdx.x * blockDim.x + tid;
    if (node >= n) return;
    float acc[NC];
    #pragma unroll
    for (int c = 0; c < NC; ++c) acc[c] = sB[c];
    const uint4* row = (const uint4*)(h + (size_t)node * D);
    #pragma unroll
    for (int q4 = 0; q4 < D / 8; ++q4) {
        uint4 v = row[q4];
        unsigned int* pv = (unsigned int*)&v;
        #pragma unroll
        for (int j = 0; j < 4; ++j) {
            int k = q4 * 8 + j * 2;
            float x0 = fmaxf(fmaf(blo(pv[j]), sSC[k], sSH[k]), 0.f);
            float x1 = fmaxf(fmaf(bhi(pv[j]), sSC[k + 1], sSH[k + 1]), 0.f);
            #pragma unroll
            for (int c = 0; c < NC; ++c)
                acc[c] += x0 * sW[k * NC + c] + x1 * sW[(k + 1) * NC + c];
        }
    }
    float* orow = out + (size_t)node * NC;
    #pragma unroll
    for (int c = 0; c < NC; ++c) orow[c] = acc[c];
}

extern "C" void kernel_launch(void* const* d_in, const int* in_sizes, int n_in,
                              void* d_out, int out_size, void* d_ws, size_t ws_size,
                              hipStream_t stream) {
    const float* x      = (const float*)d_in[0];
    const void*  eidx   = d_in[1];
    const float* w_ngh  = (const float*)d_in[2];
    const float* w_self = (const float*)d_in[3];
    const float* bias   = (const float*)d_in[4];
    const float* gamma  = (const float*)d_in[5];
    const float* beta   = (const float*)d_in[6];
    const float* clf_w  = (const float*)d_in[7];
    const float* clf_b  = (const float*)d_in[8];
    float* out = (float*)d_out;

    char* ws = (char*)d_ws;
    size_t o = 0;
    auto alloc = [&](size_t bytes) -> void* {
        void* r = ws + o;
        o += (bytes + 255) & ~(size_t)255;
        return r;
    };
    int*   flag    = (int*)alloc(4);
    int*   row_ptr = (int*)alloc((size_t)(NN + 1) * 4);
    float* inv_deg = (float*)alloc((size_t)NN * 4);
    int*   csr_src = (int*)alloc((size_t)NE * 4);
    float* stats   = (float*)alloc((size_t)NL * NREP * 2 * D * 4);
    int*   cnt     = (int*)alloc((size_t)NB * 4);
    unsigned short* wt   = (unsigned short*)alloc((size_t)NL * D * WPAD * 2);
    unsigned short* xb   = (unsigned short*)alloc((size_t)NN * D * 2);
    unsigned short* aggb = (unsigned short*)alloc((size_t)NN * D * 2);
    unsigned short* hA   = (unsigned short*)alloc((size_t)NN * D * 2);
    unsigned short* hB   = (unsigned short*)alloc((size_t)NN * D * 2);
    // binned bucket regions alias hA (dead until layer-0 GEMM writes it)
    unsigned int* binned = (unsigned int*)hA;   // NB*CAP*4 = 4.8MB <= 9.6MB

    prep_kernel<<<CASTB + PREPWB + 1, 256, 0, stream>>>(
        x, xb, w_ngh, w_self, wt, (const int*)eidx, flag, cnt, stats);
    bin_kernel<<<(NE + EPB - 1) / EPB, 256, 0, stream>>>(eidx, flag, cnt, binned, NE);
    fill_bucket_kernel<<<NB, 256, 0, stream>>>(binned, cnt, row_ptr, inv_deg, csr_src);

    const unsigned short* hin = xb;
    unsigned short* bufs[2] = {hA, hB};
    for (int l = 0; l < NL; ++l) {
        unsigned short* hout = bufs[l & 1];
        const float* st_in = stats + (size_t)(l - 1) * NREP * 2 * D;
        const float* g_in  = gamma + (size_t)(l - 1) * D;
        const float* b_in  = beta + (size_t)(l - 1) * D;
        int use_bn = (l > 0) ? 1 : 0;
        if (!use_bn) { st_in = stats; g_in = gamma; b_in = beta; }  // unread
        agg_kernel<<<(NN * 64 + 255) / 256, 256, 0, stream>>>(
            hin, row_ptr, csr_src, inv_deg, aggb, st_in, g_in, b_in, use_bn, NN);
        mfma_gemm_kernel<<<(NN + 63) / 64, 256, 0, stream>>>(
            aggb, hin, wt + (size_t)l * D * WPAD, bias + (size_t)l * D,
            hout, stats + (size_t)l * NREP * 2 * D, st_in, g_in, b_in, use_bn, NN);
        hin = hout;
    }
    clf_kernel<<<(NN + 255) / 256, 256, 0, stream>>>(
        hin, clf_w, clf_b, stats + (size_t)2 * NREP * 2 * D, gamma + (size_t)2 * D,
        beta + (size_t)2 * D, out, NN);
}

// Round 6
// 205.772 us; speedup vs baseline: 2.9882x; 1.3175x over previous
//
#include <hip/hip_runtime.h>

#define NN 50000
#define NE 800000
#define D 96
#define NL 3
#define NC 10
#define BN_EPS 1e-5f
#define INV_N (1.0f / (float)NN)
#define NB 196          // buckets of 256 dst nodes (dst >> 8)
#define CAP 6144        // max edges per bucket (mean 4082, +32 sigma)
#define EPB 2048        // edges per bin block
#define NREP 16         // stats replication factor (atomic contention)
#define WPAD 200        // padded wt row stride (shorts); 400B keeps 16B alignment
#define AGGU 16         // agg gather pipeline depth
#define CASTB ((NN * D / 4 + 255) / 256)       // 4688
#define PREPWB ((NL * D * 192 + 255) / 256)    // 216

typedef short bf16x8 __attribute__((ext_vector_type(8)));
typedef unsigned short u16x8 __attribute__((ext_vector_type(8)));
typedef float f32x4 __attribute__((ext_vector_type(4)));

// ----------------------------- bf16 helpers ---------------------------------
__device__ __forceinline__ unsigned short f2b(float x) {
    unsigned int u = __float_as_uint(x);
    unsigned int r = (u + 0x7fffu + ((u >> 16) & 1u)) >> 16;
    return (unsigned short)r;
}
__device__ __forceinline__ float blo(unsigned int u) { return __uint_as_float(u << 16); }
__device__ __forceinline__ float bhi(unsigned int u) { return __uint_as_float(u & 0xffff0000u); }
__device__ __forceinline__ float b2f(short s) {
    return __uint_as_float(((unsigned int)(unsigned short)s) << 16);
}
__device__ __forceinline__ unsigned int pk2(float lo, float hi) {
    return ((unsigned int)f2b(lo)) | (((unsigned int)f2b(hi)) << 16);
}

// ---------------- edge index access (int32 vs int64 auto-detect) -------------
__device__ __forceinline__ int edge_at(const void* idx, int is64, long long pos) {
    if (is64) return (int)((const long long*)idx)[pos];
    return ((const int*)idx)[pos];
}

// merged front-end: cast x->bf16 | build padded W_T bf16 | detect + zero
__global__ void __launch_bounds__(256) prep_kernel(
        const float* __restrict__ x, unsigned short* __restrict__ xb,
        const float* __restrict__ wn, const float* __restrict__ ws,
        unsigned short* __restrict__ wt,
        const int* __restrict__ words, int* __restrict__ flag,
        int* __restrict__ cnt, float* __restrict__ stats) {
    int b = blockIdx.x;
    int t = threadIdx.x;
    if (b < CASTB) {
        int i = b * 256 + t;
        if (i < NN * D / 4) {
            float4 v = ((const float4*)x)[i];
            ushort4 o;
            o.x = f2b(v.x); o.y = f2b(v.y); o.z = f2b(v.z); o.w = f2b(v.w);
            ((ushort4*)xb)[i] = o;
        }
        return;
    }
    if (b < CASTB + PREPWB) {
        int i = (b - CASTB) * 256 + t;
        if (i < NL * D * 192) {
            int k = i % 192;
            int col = (i / 192) % D;
            int l = i / (192 * D);
            float v = (k < D) ? wn[(size_t)l * D * D + k * D + col]
                              : ws[(size_t)l * D * D + (k - D) * D + col];
            wt[((size_t)l * D + col) * WPAD + k] = f2b(v);
        }
        return;
    }
    // last block: detect + zeros
    __shared__ int any_nz;
    if (t == 0) any_nz = 0;
    __syncthreads();
    if (words[2 * t + 1] != 0) atomicOr(&any_nz, 1);
    __syncthreads();
    if (t == 0) *flag = any_nz ? 0 : 1;   // 1 => int64
    if (t < NB) cnt[t] = 0;
    for (int i = t; i < NL * NREP * 2 * D; i += 256) stats[i] = 0.f;
}

// bucket edges by dst>>8; write (src<<8)|(dst&255) into per-bucket regions
__global__ void __launch_bounds__(256) bin_kernel(
        const void* __restrict__ idx, const int* __restrict__ flag,
        int* __restrict__ cnt, unsigned int* __restrict__ binned, int E) {
    __shared__ int hist[256];
    __shared__ int gbase[256];
    __shared__ unsigned int pk[EPB];
    __shared__ unsigned char bkt[EPB];
    int t = threadIdx.x;
    int base = blockIdx.x * EPB;
    int is64 = *flag;
    hist[t] = 0;
    __syncthreads();
    #pragma unroll
    for (int j = 0; j < 8; ++j) {
        int i = t + j * 256;
        int e = base + i;
        if (e < E) {
            int s = edge_at(idx, is64, e);
            int d = edge_at(idx, is64, (long long)E + e);
            int b = d >> 8;
            bkt[i] = (unsigned char)b;
            pk[i] = ((unsigned int)s << 8) | (unsigned int)(d & 255);
            atomicAdd(&hist[b], 1);
        } else {
            bkt[i] = 0xFF;
        }
    }
    __syncthreads();
    int h = hist[t];
    int gb = 0;
    if (t < NB && h > 0) gb = atomicAdd(&cnt[t], h);
    gbase[t] = gb;
    hist[t] = 0;
    __syncthreads();
    #pragma unroll
    for (int j = 0; j < 8; ++j) {
        int i = t + j * 256;
        int b = bkt[i];
        if (b != 0xFF) {
            int loc = atomicAdd(&hist[b], 1);
            int pos = gbase[b] + loc;
            if (pos < CAP) binned[(size_t)b * CAP + pos] = pk[i];
        }
    }
}

// per bucket: in-block scan of bucket counts -> base; LDS degree count ->
// scan -> row_ptr/inv_deg; LDS-local CSR scatter; coalesced copy-out
__global__ void __launch_bounds__(256) fill_bucket_kernel(
        const unsigned int* __restrict__ binned, const int* __restrict__ cnt,
        int* __restrict__ row_ptr, float* __restrict__ inv_deg,
        int* __restrict__ csr_src) {
    __shared__ int sexcl[256];
    __shared__ int deg_l[256];
    __shared__ int wsum[4];
    __shared__ int lds_csr[CAP];
    int b = blockIdx.x;
    int t = threadIdx.x;
    int lane = t & 63, w = t >> 6;
    {
        int v = (t < NB) ? cnt[t] : 0;
        int x = v;
        #pragma unroll
        for (int off = 1; off < 64; off <<= 1) {
            int y = __shfl_up(x, off);
            if (lane >= off) x += y;
        }
        if (lane == 63) wsum[w] = x;
        __syncthreads();
        if (t == 0) {
            int r = 0;
            #pragma unroll
            for (int i = 0; i < 4; ++i) { int tt = wsum[i]; wsum[i] = r; r += tt; }
        }
        __syncthreads();
        sexcl[t] = x - v + wsum[w];
        __syncthreads();
    }
    int base = sexcl[b];
    int count = cnt[b]; if (count > CAP) count = CAP;
    int n0 = b << 8;
    deg_l[t] = 0;
    __syncthreads();
    const unsigned int* reg = binned + (size_t)b * CAP;
    for (int i = t; i < count; i += 256) atomicAdd(&deg_l[reg[i] & 255], 1);
    __syncthreads();
    int v = deg_l[t];
    int x = v;
    #pragma unroll
    for (int off = 1; off < 64; off <<= 1) {
        int y = __shfl_up(x, off);
        if (lane >= off) x += y;
    }
    if (lane == 63) wsum[w] = x;
    __syncthreads();
    if (t == 0) {
        int r = 0;
        #pragma unroll
        for (int i = 0; i < 4; ++i) { int tt = wsum[i]; wsum[i] = r; r += tt; }
    }
    __syncthreads();
    int excl = x - v + wsum[w];
    int node = n0 + t;
    if (node < NN) {
        row_ptr[node] = base + excl;
        inv_deg[node] = 1.0f / (float)(v > 0 ? v : 1);
    }
    if (b == 0 && t == 0) row_ptr[NN] = NE;
    deg_l[t] = excl;   // reuse as fill cursor
    __syncthreads();
    for (int i = t; i < count; i += 256) {
        unsigned int pkv = reg[i];
        int loc = atomicAdd(&deg_l[pkv & 255], 1);
        lds_csr[loc] = (int)(pkv >> 8);
    }
    __syncthreads();
    for (int i = t; i < count; i += 256) csr_src[base + i] = lds_csr[i];
}

// fold NREP stat replicas -> per-feature scale/shift (one tiny block per layer)
__global__ void bn_coef_kernel(const float* __restrict__ stats,
                               const float* __restrict__ gamma,
                               const float* __restrict__ beta,
                               float* __restrict__ scsh) {
    int f = threadIdx.x;
    if (f >= D) return;
    float s = 0.f, q = 0.f;
    #pragma unroll
    for (int r = 0; r < NREP; ++r) {
        s += stats[r * 2 * D + f];
        q += stats[r * 2 * D + D + f];
    }
    float mu = s * INV_N;
    float va = q * INV_N - mu * mu;
    float sc = rsqrtf(va + BN_EPS) * gamma[f];
    scsh[f] = sc;
    scsh[D + f] = beta[f] - mu * sc;
}

// one wave per dst node; lazy BN+ReLU from precomputed scsh; 16-deep pipeline.
__global__ void agg_kernel(const unsigned short* __restrict__ hb,
                           const int* __restrict__ row_ptr,
                           const int* __restrict__ csr_src,
                           const float* __restrict__ inv_deg,
                           unsigned short* __restrict__ aggb,
                           const float* __restrict__ scsh_in,
                           int use_bn, int n) {
    int gid = blockIdx.x * blockDim.x + threadIdx.x;
    int node = gid >> 6;
    int lane = gid & 63;
    if (node >= n) return;
    bool act = lane < 48;
    float sc0 = 1.f, sh0 = 0.f, sc1 = 1.f, sh1 = 0.f;
    float lo = use_bn ? 0.f : -3.0e38f;
    if (use_bn && act) {
        float2 scp = *(const float2*)(scsh_in + lane * 2);
        float2 shp = *(const float2*)(scsh_in + D + lane * 2);
        sc0 = scp.x; sc1 = scp.y; sh0 = shp.x; sh1 = shp.y;
    }
    int beg = row_ptr[node], end = row_ptr[node + 1];
    float a0 = 0.f, a1 = 0.f, b0 = 0.f, b1 = 0.f;
    float c0 = 0.f, c1 = 0.f, d0 = 0.f, d1 = 0.f;

    int e = beg;
    int sidx[AGGU];
    #pragma unroll
    for (int j = 0; j < AGGU; ++j) sidx[j] = (e + j < end) ? csr_src[e + j] : -1;
    while (e < end) {
        int enext = e + AGGU;
        int snext[AGGU];
        #pragma unroll
        for (int j = 0; j < AGGU; ++j)
            snext[j] = (enext + j < end) ? csr_src[enext + j] : -1;
        unsigned int u[AGGU];
        #pragma unroll
        for (int j = 0; j < AGGU; ++j) {
            int s = sidx[j];
            u[j] = (s >= 0 && act)
                 ? *(const unsigned int*)(hb + (size_t)s * D + lane * 2) : 0u;
        }
        #pragma unroll
        for (int j = 0; j < AGGU; ++j) {
            if (sidx[j] >= 0) {   // wave-uniform branch
                float x0 = fmaxf(fmaf(blo(u[j]), sc0, sh0), lo);
                float x1 = fmaxf(fmaf(bhi(u[j]), sc1, sh1), lo);
                if ((j & 3) == 0) { a0 += x0; a1 += x1; }
                else if ((j & 3) == 1) { b0 += x0; b1 += x1; }
                else if ((j & 3) == 2) { c0 += x0; c1 += x1; }
                else { d0 += x0; d1 += x1; }
            }
        }
        #pragma unroll
        for (int j = 0; j < AGGU; ++j) sidx[j] = snext[j];
        e = enext;
    }
    a0 = (a0 + b0) + (c0 + d0);
    a1 = (a1 + b1) + (c1 + d1);
    if (act) {
        float idg = inv_deg[node];
        *(unsigned int*)(aggb + (size_t)node * D + lane * 2) = pk2(a0 * idg, a1 * idg);
    }
}

// MFMA GEMM + fused BN stats. B operands LDS-staged; stats atomics replicated.
__global__ void __launch_bounds__(256) mfma_gemm_kernel(
        const unsigned short* __restrict__ aggb,
        const unsigned short* __restrict__ hb,
        const unsigned short* __restrict__ wt,    // [96][WPAD] padded, this layer
        const float* __restrict__ bias,
        unsigned short* __restrict__ hout,
        float* __restrict__ stats,                // this layer, NREP replicas
        const float* __restrict__ scsh_in,        // prev layer coefs
        int use_bn, int n) {
    __shared__ float red[4][192];
    __shared__ float sSC[D];
    __shared__ float sSH[D];
    __shared__ unsigned short sW[D][WPAD];   // 38.4 KB
    int tid = threadIdx.x;
    int wave = tid >> 6;
    int lane = tid & 63;
    int m16 = lane & 15;
    int hi = lane >> 4;
    int rbase = blockIdx.x * 64 + wave * 16;

    // 1) A-fragment global loads first (12 independent b128s)
    int arow = rbase + m16;
    int arowc = arow < n ? arow : n - 1;
    const unsigned short* ap = aggb + (size_t)arowc * D + hi * 8;
    const unsigned short* hp = hb + (size_t)arowc * D + hi * 8;
    bf16x8 A[6], H[3];
    #pragma unroll
    for (int kk = 0; kk < 3; ++kk) A[kk] = *reinterpret_cast<const bf16x8*>(ap + kk * 32);
    #pragma unroll
    for (int kk = 0; kk < 3; ++kk) H[kk] = *reinterpret_cast<const bf16x8*>(hp + kk * 32);

    // 2) cooperative wt staging: 96 cols x 24 chunks of 16B, coalesced
    #pragma unroll
    for (int c = 0; c < 9; ++c) {
        int i = tid + c * 256;
        int col = i / 24, seg = i % 24;
        *reinterpret_cast<u16x8*>(&sW[col][seg * 8]) =
            *reinterpret_cast<const u16x8*>(wt + (size_t)col * WPAD + seg * 8);
    }

    // 3) previous-layer BN coefs
    if (use_bn && tid < D) {
        sSC[tid] = scsh_in[tid];
        sSH[tid] = scsh_in[D + tid];
    }
    __syncthreads();

    // 4) lazy BN+ReLU on self-term fragments
    #pragma unroll
    for (int kk = 0; kk < 3; ++kk) {
        if (use_bn) {
            bf16x8 T;
            #pragma unroll
            for (int j = 0; j < 8; ++j) {
                int f = kk * 32 + hi * 8 + j;
                float v = fmaxf(fmaf(b2f(H[kk][j]), sSC[f], sSH[f]), 0.f);
                T[j] = (short)f2b(v);
            }
            A[3 + kk] = T;
        } else {
            A[3 + kk] = H[kk];
        }
    }

    // 5) MFMA loop, B from LDS
    f32x4 acc[6];
    #pragma unroll
    for (int nn = 0; nn < 6; ++nn) acc[nn] = (f32x4){0.f, 0.f, 0.f, 0.f};
    #pragma unroll
    for (int nn = 0; nn < 6; ++nn) {
        int col = nn * 16 + m16;
        #pragma unroll
        for (int kk = 0; kk < 6; ++kk) {
            bf16x8 B = *reinterpret_cast<const bf16x8*>(&sW[col][kk * 32 + hi * 8]);
            acc[nn] = __builtin_amdgcn_mfma_f32_16x16x32_bf16(A[kk], B, acc[nn], 0, 0, 0);
        }
    }

    // 6) epilogue: bias, bf16 store, BN partial sums -> replicated atomics
    #pragma unroll
    for (int nn = 0; nn < 6; ++nn) {
        int f = nn * 16 + m16;
        float bv = bias[f];
        float s = 0.f, q = 0.f;
        #pragma unroll
        for (int r = 0; r < 4; ++r) {
            int rrow = rbase + hi * 4 + r;
            float v = acc[nn][r] + bv;
            if (rrow < n) {
                hout[(size_t)rrow * D + f] = f2b(v);
                s += v;
                q += v * v;
            }
        }
        s += __shfl_xor(s, 16); q += __shfl_xor(q, 16);
        s += __shfl_xor(s, 32); q += __shfl_xor(q, 32);
        if (lane < 16) {
            red[wave][f] = s;
            red[wave][96 + f] = q;
        }
    }
    __syncthreads();
    if (tid < 192) {
        float t = red[0][tid] + red[1][tid] + red[2][tid] + red[3][tid];
        atomicAdd(&stats[(blockIdx.x & (NREP - 1)) * 2 * D + tid], t);
    }
}

// classifier with lazy BN+ReLU of the final layer
__global__ void clf_kernel(const unsigned short* __restrict__ h,
                           const float* __restrict__ W,
                           const float* __restrict__ b,
                           const float* __restrict__ scsh_in,
                           float* __restrict__ out, int n) {
    __shared__ float sW[D * NC];
    __shared__ float sB[NC];
    __shared__ float sSC[D];
    __shared__ float sSH[D];
    int tid = threadIdx.x;
    for (int i = tid; i < D * NC; i += blockDim.x) sW[i] = W[i];
    if (tid < NC) sB[tid] = b[tid];
    if (tid < D) {
        sSC[tid] = scsh_in[tid];
        sSH[tid] = scsh_in[D + tid];
    }
    __syncthreads();
    int node = blockIdx.x * blockDim.x + tid;
    if (node >= n) return;
    float acc[NC];
    #pragma unroll
    for (int c = 0; c < NC; ++c) acc[c] = sB[c];
    const uint4* row = (const uint4*)(h + (size_t)node * D);
    #pragma unroll
    for (int q4 = 0; q4 < D / 8; ++q4) {
        uint4 v = row[q4];
        unsigned int* pv = (unsigned int*)&v;
        #pragma unroll
        for (int j = 0; j < 4; ++j) {
            int k = q4 * 8 + j * 2;
            float x0 = fmaxf(fmaf(blo(pv[j]), sSC[k], sSH[k]), 0.f);
            float x1 = fmaxf(fmaf(bhi(pv[j]), sSC[k + 1], sSH[k + 1]), 0.f);
            #pragma unroll
            for (int c = 0; c < NC; ++c)
                acc[c] += x0 * sW[k * NC + c] + x1 * sW[(k + 1) * NC + c];
        }
    }
    float* orow = out + (size_t)node * NC;
    #pragma unroll
    for (int c = 0; c < NC; ++c) orow[c] = acc[c];
}

extern "C" void kernel_launch(void* const* d_in, const int* in_sizes, int n_in,
                              void* d_out, int out_size, void* d_ws, size_t ws_size,
                              hipStream_t stream) {
    const float* x      = (const float*)d_in[0];
    const void*  eidx   = d_in[1];
    const float* w_ngh  = (const float*)d_in[2];
    const float* w_self = (const float*)d_in[3];
    const float* bias   = (const float*)d_in[4];
    const float* gamma  = (const float*)d_in[5];
    const float* beta   = (const float*)d_in[6];
    const float* clf_w  = (const float*)d_in[7];
    const float* clf_b  = (const float*)d_in[8];
    float* out = (float*)d_out;

    char* ws = (char*)d_ws;
    size_t o = 0;
    auto alloc = [&](size_t bytes) -> void* {
        void* r = ws + o;
        o += (bytes + 255) & ~(size_t)255;
        return r;
    };
    int*   flag    = (int*)alloc(4);
    int*   row_ptr = (int*)alloc((size_t)(NN + 1) * 4);
    float* inv_deg = (float*)alloc((size_t)NN * 4);
    int*   csr_src = (int*)alloc((size_t)NE * 4);
    float* stats   = (float*)alloc((size_t)NL * NREP * 2 * D * 4);
    float* scsh    = (float*)alloc((size_t)NL * 2 * D * 4);
    int*   cnt     = (int*)alloc((size_t)NB * 4);
    unsigned short* wt   = (unsigned short*)alloc((size_t)NL * D * WPAD * 2);
    unsigned short* xb   = (unsigned short*)alloc((size_t)NN * D * 2);
    unsigned short* aggb = (unsigned short*)alloc((size_t)NN * D * 2);
    unsigned short* hA   = (unsigned short*)alloc((size_t)NN * D * 2);
    unsigned short* hB   = (unsigned short*)alloc((size_t)NN * D * 2);
    // binned bucket regions alias hA (dead until layer-0 GEMM writes it)
    unsigned int* binned = (unsigned int*)hA;   // NB*CAP*4 = 4.8MB <= 9.6MB

    prep_kernel<<<CASTB + PREPWB + 1, 256, 0, stream>>>(
        x, xb, w_ngh, w_self, wt, (const int*)eidx, flag, cnt, stats);
    bin_kernel<<<(NE + EPB - 1) / EPB, 256, 0, stream>>>(eidx, flag, cnt, binned, NE);
    fill_bucket_kernel<<<NB, 256, 0, stream>>>(binned, cnt, row_ptr, inv_deg, csr_src);

    const unsigned short* hin = xb;
    unsigned short* bufs[2] = {hA, hB};
    for (int l = 0; l < NL; ++l) {
        unsigned short* hout = bufs[l & 1];
        const float* coef_in = scsh + (size_t)(l - 1) * 2 * D;
        int use_bn = (l > 0) ? 1 : 0;
        if (!use_bn) coef_in = scsh;   // unread
        agg_kernel<<<(NN * 64 + 255) / 256, 256, 0, stream>>>(
            hin, row_ptr, csr_src, inv_deg, aggb, coef_in, use_bn, NN);
        mfma_gemm_kernel<<<(NN + 63) / 64, 256, 0, stream>>>(
            aggb, hin, wt + (size_t)l * D * WPAD, bias + (size_t)l * D,
            hout, stats + (size_t)l * NREP * 2 * D, coef_in, use_bn, NN);
        bn_coef_kernel<<<1, D, 0, stream>>>(stats + (size_t)l * NREP * 2 * D,
                                            gamma + (size_t)l * D, beta + (size_t)l * D,
                                            scsh + (size_t)l * 2 * D);
        hin = hout;
    }
    clf_kernel<<<(NN + 255) / 256, 256, 0, stream>>>(
        hin, clf_w, clf_b, scsh + (size_t)2 * 2 * D, out, NN);
}

// Round 8
// 192.409 us; speedup vs baseline: 3.1958x; 1.0695x over previous
//
#include <hip/hip_runtime.h>

#define NN 50000
#define NE 800000
#define D 96
#define NL 3
#define NC 10
#define BN_EPS 1e-5f
#define INV_N (1.0f / (float)NN)
#define NB 196          // buckets of 256 dst nodes (dst >> 8)
#define CAP 6144        // max edges per bucket (mean 4082, +32 sigma)
#define EPB 2048        // edges per bin block
#define NREP 16         // stats replication factor (atomic contention)
#define WPAD 200        // padded wt row stride (shorts); 400B keeps 16B alignment
#define CASTB ((NN * D / 4 + 255) / 256)       // 4688
#define PREPWB ((NL * D * 192 + 255) / 256)    // 216

typedef _Float16 f16x8 __attribute__((ext_vector_type(8)));
typedef _Float16 h2t __attribute__((ext_vector_type(2)));
typedef unsigned short u16x8 __attribute__((ext_vector_type(8)));
typedef unsigned int u32x3 __attribute__((ext_vector_type(3)));
typedef float f32x4 __attribute__((ext_vector_type(4)));

// ----------------------------- fp16 helpers ---------------------------------
__device__ __forceinline__ unsigned short f2h(float x) {
    _Float16 h = (_Float16)x;
    return __builtin_bit_cast(unsigned short, h);
}
__device__ __forceinline__ unsigned int pkh2(float lo, float hi) {
    auto r = __builtin_amdgcn_cvt_pkrtz(lo, hi);   // __fp16 ext_vector(2)
    return __builtin_bit_cast(unsigned int, r);
}
__device__ __forceinline__ unsigned int pkadd(unsigned int a, unsigned int b) {
    h2t x = __builtin_bit_cast(h2t, a);
    h2t y = __builtin_bit_cast(h2t, b);
    h2t z = x + y;
    return __builtin_bit_cast(unsigned int, z);
}

// ---------------- edge index access (int32 vs int64 auto-detect) -------------
__device__ __forceinline__ int edge_at(const void* idx, int is64, long long pos) {
    if (is64) return (int)((const long long*)idx)[pos];
    return ((const int*)idx)[pos];
}

// merged front-end: cast x->fp16 | build padded W_T fp16 | detect + zero
__global__ void __launch_bounds__(256) prep_kernel(
        const float* __restrict__ x, unsigned short* __restrict__ xb,
        const float* __restrict__ wn, const float* __restrict__ ws,
        unsigned short* __restrict__ wt,
        const int* __restrict__ words, int* __restrict__ flag,
        int* __restrict__ cnt, float* __restrict__ stats) {
    int b = blockIdx.x;
    int t = threadIdx.x;
    if (b < CASTB) {
        int i = b * 256 + t;
        if (i < NN * D / 4) {
            float4 v = ((const float4*)x)[i];
            ushort4 o;
            o.x = f2h(v.x); o.y = f2h(v.y); o.z = f2h(v.z); o.w = f2h(v.w);
            ((ushort4*)xb)[i] = o;
        }
        return;
    }
    if (b < CASTB + PREPWB) {
        int i = (b - CASTB) * 256 + t;
        if (i < NL * D * 192) {
            int k = i % 192;
            int col = (i / 192) % D;
            int l = i / (192 * D);
            float v = (k < D) ? wn[(size_t)l * D * D + k * D + col]
                              : ws[(size_t)l * D * D + (k - D) * D + col];
            wt[((size_t)l * D + col) * WPAD + k] = f2h(v);
        }
        return;
    }
    // last block: detect + zeros
    __shared__ int any_nz;
    if (t == 0) any_nz = 0;
    __syncthreads();
    if (words[2 * t + 1] != 0) atomicOr(&any_nz, 1);
    __syncthreads();
    if (t == 0) *flag = any_nz ? 0 : 1;   // 1 => int64
    if (t < NB) cnt[t] = 0;
    for (int i = t; i < NL * NREP * 2 * D; i += 256) stats[i] = 0.f;
}

// bucket edges by dst>>8; write (src<<8)|(dst&255) into per-bucket regions
__global__ void __launch_bounds__(256) bin_kernel(
        const void* __restrict__ idx, const int* __restrict__ flag,
        int* __restrict__ cnt, unsigned int* __restrict__ binned, int E) {
    __shared__ int hist[256];
    __shared__ int gbase[256];
    __shared__ unsigned int pk[EPB];
    __shared__ unsigned char bkt[EPB];
    int t = threadIdx.x;
    int base = blockIdx.x * EPB;
    int is64 = *flag;
    hist[t] = 0;
    __syncthreads();
    #pragma unroll
    for (int j = 0; j < 8; ++j) {
        int i = t + j * 256;
        int e = base + i;
        if (e < E) {
            int s = edge_at(idx, is64, e);
            int d = edge_at(idx, is64, (long long)E + e);
            int b = d >> 8;
            bkt[i] = (unsigned char)b;
            pk[i] = ((unsigned int)s << 8) | (unsigned int)(d & 255);
            atomicAdd(&hist[b], 1);
        } else {
            bkt[i] = 0xFF;
        }
    }
    __syncthreads();
    int h = hist[t];
    int gb = 0;
    if (t < NB && h > 0) gb = atomicAdd(&cnt[t], h);
    gbase[t] = gb;
    hist[t] = 0;
    __syncthreads();
    #pragma unroll
    for (int j = 0; j < 8; ++j) {
        int i = t + j * 256;
        int b = bkt[i];
        if (b != 0xFF) {
            int loc = atomicAdd(&hist[b], 1);
            int pos = gbase[b] + loc;
            if (pos < CAP) binned[(size_t)b * CAP + pos] = pk[i];
        }
    }
}

// per bucket: in-block scan of bucket counts -> base; LDS degree count ->
// scan -> row_ptr/inv_deg; LDS-local CSR scatter; coalesced copy-out
__global__ void __launch_bounds__(256) fill_bucket_kernel(
        const unsigned int* __restrict__ binned, const int* __restrict__ cnt,
        int* __restrict__ row_ptr, float* __restrict__ inv_deg,
        int* __restrict__ csr_src) {
    __shared__ int sexcl[256];
    __shared__ int deg_l[256];
    __shared__ int wsum[4];
    __shared__ int lds_csr[CAP];
    int b = blockIdx.x;
    int t = threadIdx.x;
    int lane = t & 63, w = t >> 6;
    {
        int v = (t < NB) ? cnt[t] : 0;
        int x = v;
        #pragma unroll
        for (int off = 1; off < 64; off <<= 1) {
            int y = __shfl_up(x, off);
            if (lane >= off) x += y;
        }
        if (lane == 63) wsum[w] = x;
        __syncthreads();
        if (t == 0) {
            int r = 0;
            #pragma unroll
            for (int i = 0; i < 4; ++i) { int tt = wsum[i]; wsum[i] = r; r += tt; }
        }
        __syncthreads();
        sexcl[t] = x - v + wsum[w];
        __syncthreads();
    }
    int base = sexcl[b];
    int count = cnt[b]; if (count > CAP) count = CAP;
    int n0 = b << 8;
    deg_l[t] = 0;
    __syncthreads();
    const unsigned int* reg = binned + (size_t)b * CAP;
    for (int i = t; i < count; i += 256) atomicAdd(&deg_l[reg[i] & 255], 1);
    __syncthreads();
    int v = deg_l[t];
    int x = v;
    #pragma unroll
    for (int off = 1; off < 64; off <<= 1) {
        int y = __shfl_up(x, off);
        if (lane >= off) x += y;
    }
    if (lane == 63) wsum[w] = x;
    __syncthreads();
    if (t == 0) {
        int r = 0;
        #pragma unroll
        for (int i = 0; i < 4; ++i) { int tt = wsum[i]; wsum[i] = r; r += tt; }
    }
    __syncthreads();
    int excl = x - v + wsum[w];
    int node = n0 + t;
    if (node < NN) {
        row_ptr[node] = base + excl;
        inv_deg[node] = 1.0f / (float)(v > 0 ? v : 1);
    }
    if (b == 0 && t == 0) row_ptr[NN] = NE;
    deg_l[t] = excl;   // reuse as fill cursor
    __syncthreads();
    for (int i = t; i < count; i += 256) {
        unsigned int pkv = reg[i];
        int loc = atomicAdd(&deg_l[pkv & 255], 1);
        lds_csr[loc] = (int)(pkv >> 8);
    }
    __syncthreads();
    for (int i = t; i < count; i += 256) csr_src[base + i] = lds_csr[i];
}

// fold NREP stat replicas -> per-feature scale/shift (one tiny block per layer)
__global__ void bn_coef_kernel(const float* __restrict__ stats,
                               const float* __restrict__ gamma,
                               const float* __restrict__ beta,
                               float* __restrict__ scsh) {
    int f = threadIdx.x;
    if (f >= D) return;
    float s = 0.f, q = 0.f;
    #pragma unroll
    for (int r = 0; r < NREP; ++r) {
        s += stats[r * 2 * D + f];
        q += stats[r * 2 * D + D + f];
    }
    float mu = s * INV_N;
    float va = q * INV_N - mu * mu;
    float sc = rsqrtf(va + BN_EPS) * gamma[f];
    scsh[f] = sc;
    scsh[D + f] = beta[f] - mu * sc;
}

// materialize post-BN+ReLU fp16 h (one elementwise pass per layer)
__global__ void __launch_bounds__(256) bn_apply_kernel(
        const unsigned short* __restrict__ hpre,
        const float* __restrict__ scsh,
        unsigned short* __restrict__ hpost) {
    __shared__ float sC[2 * D];
    int t = threadIdx.x;
    if (t < 2 * D) sC[t] = scsh[t];
    __syncthreads();
    int i = blockIdx.x * 256 + t;
    if (i >= NN * D / 8) return;
    uint4 v = ((const uint4*)hpre)[i];
    int f0 = (i * 8) % D;
    unsigned int* pv = (unsigned int*)&v;
    uint4 o;
    unsigned int* po = (unsigned int*)&o;
    #pragma unroll
    for (int j = 0; j < 4; ++j) {
        int f = f0 + 2 * j;
        h2t a = __builtin_bit_cast(h2t, pv[j]);
        float x0 = fmaxf(fmaf((float)a.x, sC[f], sC[D + f]), 0.f);
        float x1 = fmaxf(fmaf((float)a.y, sC[f + 1], sC[D + f + 1]), 0.f);
        po[j] = pkh2(x0, x1);
    }
    ((uint4*)hpost)[i] = o;
}

// one wave per dst node: 4 groups x 16 lanes, each group one edge, lane owns
// 12 bytes (6 fp16). Packed fp16 accumulate; cross-group shfl reduce at end.
__global__ void agg_kernel(const unsigned short* __restrict__ hb,
                           const int* __restrict__ row_ptr,
                           const int* __restrict__ csr_src,
                           const float* __restrict__ inv_deg,
                           unsigned short* __restrict__ aggb, int n) {
    int gid = blockIdx.x * blockDim.x + threadIdx.x;
    int node = gid >> 6;
    int lane = gid & 63;
    if (node >= n) return;
    int g = lane >> 4;          // edge slot 0..3
    unsigned int p12 = (lane & 15) * 12u;  // byte offset within row
    int beg = row_ptr[node], end = row_ptr[node + 1];
    const char* hbase = (const char*)hb;

    u32x3 acc0 = {0, 0, 0}, acc1 = {0, 0, 0};
    int e = beg;
    int i0 = (beg + g < end) ? csr_src[beg + g] : -1;
    int i1 = (beg + 4 + g < end) ? csr_src[beg + 4 + g] : -1;
    while (e < end) {
        u32x3 u0 = {0, 0, 0}, u1 = {0, 0, 0};
        if (i0 >= 0) u0 = *(const u32x3*)(hbase + (unsigned)i0 * 192u + p12);
        if (i1 >= 0) u1 = *(const u32x3*)(hbase + (unsigned)i1 * 192u + p12);
        int en = e + 8;
        i0 = (en + g < end) ? csr_src[en + g] : -1;
        i1 = (en + 4 + g < end) ? csr_src[en + 4 + g] : -1;
        #pragma unroll
        for (int r = 0; r < 3; ++r) {
            acc0[r] = pkadd(acc0[r], u0[r]);
            acc1[r] = pkadd(acc1[r], u1[r]);
        }
        e = en;
    }
    // combine slots + cross-group reduce (lanes L, L+16, L+32, L+48)
    unsigned int acc[3];
    #pragma unroll
    for (int r = 0; r < 3; ++r) {
        unsigned int a = pkadd(acc0[r], acc1[r]);
        a = pkadd(a, (unsigned int)__shfl_xor((int)a, 16));
        a = pkadd(a, (unsigned int)__shfl_xor((int)a, 32));
        acc[r] = a;
    }
    if (lane < 16) {
        float idg = inv_deg[node];
        u32x3 o;
        #pragma unroll
        for (int r = 0; r < 3; ++r) {
            h2t a = __builtin_bit_cast(h2t, acc[r]);
            o[r] = pkh2((float)a.x * idg, (float)a.y * idg);
        }
        *(u32x3*)((char*)aggb + (unsigned)node * 192u + p12) = o;
    }
}

// MFMA fp16 GEMM + fused BN stats. B operands LDS-staged; replicated atomics.
__global__ void __launch_bounds__(256) mfma_gemm_kernel(
        const unsigned short* __restrict__ aggb,
        const unsigned short* __restrict__ hb,     // post-BN (or xb for l=0)
        const unsigned short* __restrict__ wt,     // [96][WPAD] padded fp16
        const float* __restrict__ bias,
        unsigned short* __restrict__ hout,         // pre-BN fp16
        float* __restrict__ stats,                 // NREP replicas
        int n) {
    __shared__ float red[4][192];
    __shared__ unsigned short sW[D][WPAD];   // 38.4 KB
    int tid = threadIdx.x;
    int wave = tid >> 6;
    int lane = tid & 63;
    int m16 = lane & 15;
    int hi = lane >> 4;
    int rbase = blockIdx.x * 64 + wave * 16;

    // 1) A-fragment global loads first (12 independent b128s)
    int arow = rbase + m16;
    int arowc = arow < n ? arow : n - 1;
    const unsigned short* ap = aggb + (size_t)arowc * D + hi * 8;
    const unsigned short* hp = hb + (size_t)arowc * D + hi * 8;
    f16x8 A[6];
    #pragma unroll
    for (int kk = 0; kk < 3; ++kk) A[kk] = *reinterpret_cast<const f16x8*>(ap + kk * 32);
    #pragma unroll
    for (int kk = 0; kk < 3; ++kk) A[3 + kk] = *reinterpret_cast<const f16x8*>(hp + kk * 32);

    // 2) cooperative wt staging: 96 cols x 24 chunks of 16B, coalesced
    #pragma unroll
    for (int c = 0; c < 9; ++c) {
        int i = tid + c * 256;
        int col = i / 24, seg = i % 24;
        *reinterpret_cast<u16x8*>(&sW[col][seg * 8]) =
            *reinterpret_cast<const u16x8*>(wt + (size_t)col * WPAD + seg * 8);
    }
    __syncthreads();

    // 3) MFMA loop, B from LDS
    f32x4 acc[6];
    #pragma unroll
    for (int nn = 0; nn < 6; ++nn) acc[nn] = (f32x4){0.f, 0.f, 0.f, 0.f};
    #pragma unroll
    for (int nn = 0; nn < 6; ++nn) {
        int col = nn * 16 + m16;
        #pragma unroll
        for (int kk = 0; kk < 6; ++kk) {
            f16x8 B = *reinterpret_cast<const f16x8*>(&sW[col][kk * 32 + hi * 8]);
            acc[nn] = __builtin_amdgcn_mfma_f32_16x16x32_f16(A[kk], B, acc[nn], 0, 0, 0);
        }
    }

    // 4) epilogue: bias, fp16 store, BN partial sums -> replicated atomics
    #pragma unroll
    for (int nn = 0; nn < 6; ++nn) {
        int f = nn * 16 + m16;
        float bv = bias[f];
        float s = 0.f, q = 0.f;
        #pragma unroll
        for (int r = 0; r < 4; ++r) {
            int rrow = rbase + hi * 4 + r;
            float v = acc[nn][r] + bv;
            if (rrow < n) {
                hout[(size_t)rrow * D + f] = f2h(v);
                s += v;
                q += v * v;
            }
        }
        s += __shfl_xor(s, 16); q += __shfl_xor(q, 16);
        s += __shfl_xor(s, 32); q += __shfl_xor(q, 32);
        if (lane < 16) {
            red[wave][f] = s;
            red[wave][96 + f] = q;
        }
    }
    __syncthreads();
    if (tid < 192) {
        float t = red[0][tid] + red[1][tid] + red[2][tid] + red[3][tid];
        atomicAdd(&stats[(blockIdx.x & (NREP - 1)) * 2 * D + tid], t);
    }
}

// classifier (input already post-BN fp16)
__global__ void clf_kernel(const unsigned short* __restrict__ h,
                           const float* __restrict__ W,
                           const float* __restrict__ b,
                           float* __restrict__ out, int n) {
    __shared__ float sW[D * NC];
    __shared__ float sB[NC];
    int tid = threadIdx.x;
    for (int i = tid; i < D * NC; i += blockDim.x) sW[i] = W[i];
    if (tid < NC) sB[tid] = b[tid];
    __syncthreads();
    int node = blockIdx.x * blockDim.x + tid;
    if (node >= n) return;
    float acc[NC];
    #pragma unroll
    for (int c = 0; c < NC; ++c) acc[c] = sB[c];
    const uint4* row = (const uint4*)(h + (size_t)node * D);
    #pragma unroll
    for (int q4 = 0; q4 < D / 8; ++q4) {
        uint4 v = row[q4];
        unsigned int* pv = (unsigned int*)&v;
        #pragma unroll
        for (int j = 0; j < 4; ++j) {
            int k = q4 * 8 + j * 2;
            h2t a = __builtin_bit_cast(h2t, pv[j]);
            float x0 = (float)a.x;
            float x1 = (float)a.y;
            #pragma unroll
            for (int c = 0; c < NC; ++c)
                acc[c] += x0 * sW[k * NC + c] + x1 * sW[(k + 1) * NC + c];
        }
    }
    float* orow = out + (size_t)node * NC;
    #pragma unroll
    for (int c = 0; c < NC; ++c) orow[c] = acc[c];
}

extern "C" void kernel_launch(void* const* d_in, const int* in_sizes, int n_in,
                              void* d_out, int out_size, void* d_ws, size_t ws_size,
                              hipStream_t stream) {
    const float* x      = (const float*)d_in[0];
    const void*  eidx   = d_in[1];
    const float* w_ngh  = (const float*)d_in[2];
    const float* w_self = (const float*)d_in[3];
    const float* bias   = (const float*)d_in[4];
    const float* gamma  = (const float*)d_in[5];
    const float* beta   = (const float*)d_in[6];
    const float* clf_w  = (const float*)d_in[7];
    const float* clf_b  = (const float*)d_in[8];
    float* out = (float*)d_out;

    char* ws = (char*)d_ws;
    size_t o = 0;
    auto alloc = [&](size_t bytes) -> void* {
        void* r = ws + o;
        o += (bytes + 255) & ~(size_t)255;
        return r;
    };
    int*   flag    = (int*)alloc(4);
    int*   row_ptr = (int*)alloc((size_t)(NN + 1) * 4);
    float* inv_deg = (float*)alloc((size_t)NN * 4);
    int*   csr_src = (int*)alloc((size_t)NE * 4);
    float* stats   = (float*)alloc((size_t)NL * NREP * 2 * D * 4);
    float* scsh    = (float*)alloc((size_t)NL * 2 * D * 4);
    int*   cnt     = (int*)alloc((size_t)NB * 4);
    unsigned short* wt   = (unsigned short*)alloc((size_t)NL * D * WPAD * 2);
    unsigned short* xb   = (unsigned short*)alloc((size_t)NN * D * 2);
    unsigned short* aggb = (unsigned short*)alloc((size_t)NN * D * 2);
    unsigned short* hpre = (unsigned short*)alloc((size_t)NN * D * 2);
    unsigned short* hpA  = (unsigned short*)alloc((size_t)NN * D * 2);
    unsigned short* hpB  = (unsigned short*)alloc((size_t)NN * D * 2);
    // binned bucket regions alias hpA (dead until layer-0 bn_apply writes it)
    unsigned int* binned = (unsigned int*)hpA;   // NB*CAP*4 = 4.8MB <= 9.6MB

    prep_kernel<<<CASTB + PREPWB + 1, 256, 0, stream>>>(
        x, xb, w_ngh, w_self, wt, (const int*)eidx, flag, cnt, stats);
    bin_kernel<<<(NE + EPB - 1) / EPB, 256, 0, stream>>>(eidx, flag, cnt, binned, NE);
    fill_bucket_kernel<<<NB, 256, 0, stream>>>(binned, cnt, row_ptr, inv_deg, csr_src);

    const unsigned short* hin = xb;   // layer input (post-BN for l>0)
    unsigned short* hpost[NL] = {hpA, hpB, hpA};
    for (int l = 0; l < NL; ++l) {
        agg_kernel<<<(NN * 64 + 255) / 256, 256, 0, stream>>>(
            hin, row_ptr, csr_src, inv_deg, aggb, NN);
        mfma_gemm_kernel<<<(NN + 63) / 64, 256, 0, stream>>>(
            aggb, hin, wt + (size_t)l * D * WPAD, bias + (size_t)l * D,
            hpre, stats + (size_t)l * NREP * 2 * D, NN);
        bn_coef_kernel<<<1, D, 0, stream>>>(stats + (size_t)l * NREP * 2 * D,
                                            gamma + (size_t)l * D, beta + (size_t)l * D,
                                            scsh + (size_t)l * 2 * D);
        bn_apply_kernel<<<(NN * D / 8 + 255) / 256, 256, 0, stream>>>(
            hpre, scsh + (size_t)l * 2 * D, hpost[l]);
        hin = hpost[l];
    }
    clf_kernel<<<(NN + 255) / 256, 256, 0, stream>>>(hin, clf_w, clf_b, out, NN);
}

// Round 9
// 179.032 us; speedup vs baseline: 3.4346x; 1.0747x over previous
//
#include <hip/hip_runtime.h>

#define NN 50000
#define NE 800000
#define D 96
#define NL 3
#define NC 10
#define BN_EPS 1e-5f
#define INV_N (1.0f / (float)NN)
#define NB 196          // buckets of 256 dst nodes (dst >> 8)
#define CAP 6144        // max edges per bucket (mean 4082, +32 sigma)
#define EPB 2048        // edges per bin block
#define NREP 16         // stats replication factor (atomic contention)
#define WPAD 200        // padded wt row stride (shorts); 400B keeps 16B alignment
#define CASTB ((NN * D / 4 + 255) / 256)       // 4688
#define PREPWB ((NL * D * 192 + 255) / 256)    // 216

typedef _Float16 f16x8 __attribute__((ext_vector_type(8)));
typedef _Float16 h2t __attribute__((ext_vector_type(2)));
typedef unsigned short u16x8 __attribute__((ext_vector_type(8)));
typedef unsigned int u32x3 __attribute__((ext_vector_type(3)));
typedef float f32x4 __attribute__((ext_vector_type(4)));

// ----------------------------- fp16 helpers ---------------------------------
__device__ __forceinline__ unsigned short f2h(float x) {
    _Float16 h = (_Float16)x;
    return __builtin_bit_cast(unsigned short, h);
}
__device__ __forceinline__ unsigned int pkh2(float lo, float hi) {
    auto r = __builtin_amdgcn_cvt_pkrtz(lo, hi);   // __fp16 ext_vector(2)
    return __builtin_bit_cast(unsigned int, r);
}
__device__ __forceinline__ unsigned int pkadd(unsigned int a, unsigned int b) {
    h2t x = __builtin_bit_cast(h2t, a);
    h2t y = __builtin_bit_cast(h2t, b);
    h2t z = x + y;
    return __builtin_bit_cast(unsigned int, z);
}

// ---------------- edge index access (int32 vs int64 auto-detect) -------------
__device__ __forceinline__ int edge_at(const void* idx, int is64, long long pos) {
    if (is64) return (int)((const long long*)idx)[pos];
    return ((const int*)idx)[pos];
}

// fold NREP stat replicas -> LDS scale/shift (called by every block; L2-hot)
__device__ __forceinline__ void bn_fold(const float* __restrict__ stats,
                                        const float* __restrict__ gamma,
                                        const float* __restrict__ beta,
                                        float* sC, int t) {
    if (t < D) {
        float s = 0.f, q = 0.f;
        #pragma unroll
        for (int r = 0; r < NREP; ++r) {
            s += stats[r * 2 * D + t];
            q += stats[r * 2 * D + D + t];
        }
        float mu = s * INV_N;
        float va = q * INV_N - mu * mu;
        float sc = rsqrtf(va + BN_EPS) * gamma[t];
        sC[t] = sc;
        sC[D + t] = beta[t] - mu * sc;
    }
}

// merged front-end: cast x->fp16 | build padded W_T fp16 | detect + zero
__global__ void __launch_bounds__(256) prep_kernel(
        const float* __restrict__ x, unsigned short* __restrict__ xb,
        const float* __restrict__ wn, const float* __restrict__ ws,
        unsigned short* __restrict__ wt,
        const int* __restrict__ words, int* __restrict__ flag,
        int* __restrict__ cnt, float* __restrict__ stats) {
    int b = blockIdx.x;
    int t = threadIdx.x;
    if (b < CASTB) {
        int i = b * 256 + t;
        if (i < NN * D / 4) {
            float4 v = ((const float4*)x)[i];
            ushort4 o;
            o.x = f2h(v.x); o.y = f2h(v.y); o.z = f2h(v.z); o.w = f2h(v.w);
            ((ushort4*)xb)[i] = o;
        }
        return;
    }
    if (b < CASTB + PREPWB) {
        int i = (b - CASTB) * 256 + t;
        if (i < NL * D * 192) {
            int k = i % 192;
            int col = (i / 192) % D;
            int l = i / (192 * D);
            float v = (k < D) ? wn[(size_t)l * D * D + k * D + col]
                              : ws[(size_t)l * D * D + (k - D) * D + col];
            wt[((size_t)l * D + col) * WPAD + k] = f2h(v);
        }
        return;
    }
    // last block: detect + zeros
    __shared__ int any_nz;
    if (t == 0) any_nz = 0;
    __syncthreads();
    if (words[2 * t + 1] != 0) atomicOr(&any_nz, 1);
    __syncthreads();
    if (t == 0) *flag = any_nz ? 0 : 1;   // 1 => int64
    if (t < NB) cnt[t] = 0;
    for (int i = t; i < NL * NREP * 2 * D; i += 256) stats[i] = 0.f;
}

// bucket edges by dst>>8; write (src<<8)|(dst&255) into per-bucket regions
__global__ void __launch_bounds__(256) bin_kernel(
        const void* __restrict__ idx, const int* __restrict__ flag,
        int* __restrict__ cnt, unsigned int* __restrict__ binned, int E) {
    __shared__ int hist[256];
    __shared__ int gbase[256];
    __shared__ unsigned int pk[EPB];
    __shared__ unsigned char bkt[EPB];
    int t = threadIdx.x;
    int base = blockIdx.x * EPB;
    int is64 = *flag;
    hist[t] = 0;
    __syncthreads();
    #pragma unroll
    for (int j = 0; j < 8; ++j) {
        int i = t + j * 256;
        int e = base + i;
        if (e < E) {
            int s = edge_at(idx, is64, e);
            int d = edge_at(idx, is64, (long long)E + e);
            int b = d >> 8;
            bkt[i] = (unsigned char)b;
            pk[i] = ((unsigned int)s << 8) | (unsigned int)(d & 255);
            atomicAdd(&hist[b], 1);
        } else {
            bkt[i] = 0xFF;
        }
    }
    __syncthreads();
    int h = hist[t];
    int gb = 0;
    if (t < NB && h > 0) gb = atomicAdd(&cnt[t], h);
    gbase[t] = gb;
    hist[t] = 0;
    __syncthreads();
    #pragma unroll
    for (int j = 0; j < 8; ++j) {
        int i = t + j * 256;
        int b = bkt[i];
        if (b != 0xFF) {
            int loc = atomicAdd(&hist[b], 1);
            int pos = gbase[b] + loc;
            if (pos < CAP) binned[(size_t)b * CAP + pos] = pk[i];
        }
    }
}

// per bucket: in-block scan of bucket counts -> base; LDS degree count ->
// scan -> row_ptr/inv_deg; LDS-local CSR scatter; coalesced copy-out
__global__ void __launch_bounds__(256) fill_bucket_kernel(
        const unsigned int* __restrict__ binned, const int* __restrict__ cnt,
        int* __restrict__ row_ptr, float* __restrict__ inv_deg,
        int* __restrict__ csr_src) {
    __shared__ int sexcl[256];
    __shared__ int deg_l[256];
    __shared__ int wsum[4];
    __shared__ int lds_csr[CAP];
    int b = blockIdx.x;
    int t = threadIdx.x;
    int lane = t & 63, w = t >> 6;
    {
        int v = (t < NB) ? cnt[t] : 0;
        int x = v;
        #pragma unroll
        for (int off = 1; off < 64; off <<= 1) {
            int y = __shfl_up(x, off);
            if (lane >= off) x += y;
        }
        if (lane == 63) wsum[w] = x;
        __syncthreads();
        if (t == 0) {
            int r = 0;
            #pragma unroll
            for (int i = 0; i < 4; ++i) { int tt = wsum[i]; wsum[i] = r; r += tt; }
        }
        __syncthreads();
        sexcl[t] = x - v + wsum[w];
        __syncthreads();
    }
    int base = sexcl[b];
    int count = cnt[b]; if (count > CAP) count = CAP;
    int n0 = b << 8;
    deg_l[t] = 0;
    __syncthreads();
    const unsigned int* reg = binned + (size_t)b * CAP;
    for (int i = t; i < count; i += 256) atomicAdd(&deg_l[reg[i] & 255], 1);
    __syncthreads();
    int v = deg_l[t];
    int x = v;
    #pragma unroll
    for (int off = 1; off < 64; off <<= 1) {
        int y = __shfl_up(x, off);
        if (lane >= off) x += y;
    }
    if (lane == 63) wsum[w] = x;
    __syncthreads();
    if (t == 0) {
        int r = 0;
        #pragma unroll
        for (int i = 0; i < 4; ++i) { int tt = wsum[i]; wsum[i] = r; r += tt; }
    }
    __syncthreads();
    int excl = x - v + wsum[w];
    int node = n0 + t;
    if (node < NN) {
        row_ptr[node] = base + excl;
        inv_deg[node] = 1.0f / (float)(v > 0 ? v : 1);
    }
    if (b == 0 && t == 0) row_ptr[NN] = NE;
    deg_l[t] = excl;   // reuse as fill cursor
    __syncthreads();
    for (int i = t; i < count; i += 256) {
        unsigned int pkv = reg[i];
        int loc = atomicAdd(&deg_l[pkv & 255], 1);
        lds_csr[loc] = (int)(pkv >> 8);
    }
    __syncthreads();
    for (int i = t; i < count; i += 256) csr_src[base + i] = lds_csr[i];
}

// materialize post-BN+ReLU fp16 h; BN coefs folded in-block from replicas
__global__ void __launch_bounds__(256) bn_apply_kernel(
        const unsigned short* __restrict__ hpre,
        const float* __restrict__ stats,
        const float* __restrict__ gamma,
        const float* __restrict__ beta,
        unsigned short* __restrict__ hpost) {
    __shared__ float sC[2 * D];
    int t = threadIdx.x;
    bn_fold(stats, gamma, beta, sC, t);
    __syncthreads();
    int i = blockIdx.x * 256 + t;
    if (i >= NN * D / 8) return;
    uint4 v = ((const uint4*)hpre)[i];
    int f0 = (i * 8) % D;
    unsigned int* pv = (unsigned int*)&v;
    uint4 o;
    unsigned int* po = (unsigned int*)&o;
    #pragma unroll
    for (int j = 0; j < 4; ++j) {
        int f = f0 + 2 * j;
        h2t a = __builtin_bit_cast(h2t, pv[j]);
        float x0 = fmaxf(fmaf((float)a.x, sC[f], sC[D + f]), 0.f);
        float x1 = fmaxf(fmaf((float)a.y, sC[f + 1], sC[D + f + 1]), 0.f);
        po[j] = pkh2(x0, x1);
    }
    ((uint4*)hpost)[i] = o;
}

// one wave per dst node: 4 groups x 16 lanes, each group one edge, lane owns
// 12 bytes (6 fp16). Packed fp16 accumulate; cross-group shfl reduce at end.
__global__ void agg_kernel(const unsigned short* __restrict__ hb,
                           const int* __restrict__ row_ptr,
                           const int* __restrict__ csr_src,
                           const float* __restrict__ inv_deg,
                           unsigned short* __restrict__ aggb, int n) {
    int gid = blockIdx.x * blockDim.x + threadIdx.x;
    int node = gid >> 6;
    int lane = gid & 63;
    if (node >= n) return;
    int g = lane >> 4;          // edge slot 0..3
    unsigned int p12 = (lane & 15) * 12u;  // byte offset within row
    int beg = row_ptr[node], end = row_ptr[node + 1];
    const char* hbase = (const char*)hb;

    u32x3 acc0 = {0, 0, 0}, acc1 = {0, 0, 0};
    int e = beg;
    int i0 = (beg + g < end) ? csr_src[beg + g] : -1;
    int i1 = (beg + 4 + g < end) ? csr_src[beg + 4 + g] : -1;
    while (e < end) {
        u32x3 u0 = {0, 0, 0}, u1 = {0, 0, 0};
        if (i0 >= 0) u0 = *(const u32x3*)(hbase + (unsigned)i0 * 192u + p12);
        if (i1 >= 0) u1 = *(const u32x3*)(hbase + (unsigned)i1 * 192u + p12);
        int en = e + 8;
        i0 = (en + g < end) ? csr_src[en + g] : -1;
        i1 = (en + 4 + g < end) ? csr_src[en + 4 + g] : -1;
        #pragma unroll
        for (int r = 0; r < 3; ++r) {
            acc0[r] = pkadd(acc0[r], u0[r]);
            acc1[r] = pkadd(acc1[r], u1[r]);
        }
        e = en;
    }
    // combine slots + cross-group reduce (lanes L, L+16, L+32, L+48)
    unsigned int acc[3];
    #pragma unroll
    for (int r = 0; r < 3; ++r) {
        unsigned int a = pkadd(acc0[r], acc1[r]);
        a = pkadd(a, (unsigned int)__shfl_xor((int)a, 16));
        a = pkadd(a, (unsigned int)__shfl_xor((int)a, 32));
        acc[r] = a;
    }
    if (lane < 16) {
        float idg = inv_deg[node];
        u32x3 o;
        #pragma unroll
        for (int r = 0; r < 3; ++r) {
            h2t a = __builtin_bit_cast(h2t, acc[r]);
            o[r] = pkh2((float)a.x * idg, (float)a.y * idg);
        }
        *(u32x3*)((char*)aggb + (unsigned)node * 192u + p12) = o;
    }
}

// MFMA fp16 GEMM + fused BN stats. B operands LDS-staged; replicated atomics.
__global__ void __launch_bounds__(256) mfma_gemm_kernel(
        const unsigned short* __restrict__ aggb,
        const unsigned short* __restrict__ hb,     // post-BN (or xb for l=0)
        const unsigned short* __restrict__ wt,     // [96][WPAD] padded fp16
        const float* __restrict__ bias,
        unsigned short* __restrict__ hout,         // pre-BN fp16
        float* __restrict__ stats,                 // NREP replicas
        int n) {
    __shared__ float red[4][192];
    __shared__ unsigned short sW[D][WPAD];   // 38.4 KB
    int tid = threadIdx.x;
    int wave = tid >> 6;
    int lane = tid & 63;
    int m16 = lane & 15;
    int hi = lane >> 4;
    int rbase = blockIdx.x * 64 + wave * 16;

    // 1) A-fragment global loads first (12 independent b128s)
    int arow = rbase + m16;
    int arowc = arow < n ? arow : n - 1;
    const unsigned short* ap = aggb + (size_t)arowc * D + hi * 8;
    const unsigned short* hp = hb + (size_t)arowc * D + hi * 8;
    f16x8 A[6];
    #pragma unroll
    for (int kk = 0; kk < 3; ++kk) A[kk] = *reinterpret_cast<const f16x8*>(ap + kk * 32);
    #pragma unroll
    for (int kk = 0; kk < 3; ++kk) A[3 + kk] = *reinterpret_cast<const f16x8*>(hp + kk * 32);

    // 2) cooperative wt staging: 96 cols x 24 chunks of 16B, coalesced
    #pragma unroll
    for (int c = 0; c < 9; ++c) {
        int i = tid + c * 256;
        int col = i / 24, seg = i % 24;
        *reinterpret_cast<u16x8*>(&sW[col][seg * 8]) =
            *reinterpret_cast<const u16x8*>(wt + (size_t)col * WPAD + seg * 8);
    }
    __syncthreads();

    // 3) MFMA loop, B from LDS
    f32x4 acc[6];
    #pragma unroll
    for (int nn = 0; nn < 6; ++nn) acc[nn] = (f32x4){0.f, 0.f, 0.f, 0.f};
    #pragma unroll
    for (int nn = 0; nn < 6; ++nn) {
        int col = nn * 16 + m16;
        #pragma unroll
        for (int kk = 0; kk < 6; ++kk) {
            f16x8 B = *reinterpret_cast<const f16x8*>(&sW[col][kk * 32 + hi * 8]);
            acc[nn] = __builtin_amdgcn_mfma_f32_16x16x32_f16(A[kk], B, acc[nn], 0, 0, 0);
        }
    }

    // 4) epilogue: bias, fp16 store, BN partial sums -> replicated atomics
    #pragma unroll
    for (int nn = 0; nn < 6; ++nn) {
        int f = nn * 16 + m16;
        float bv = bias[f];
        float s = 0.f, q = 0.f;
        #pragma unroll
        for (int r = 0; r < 4; ++r) {
            int rrow = rbase + hi * 4 + r;
            float v = acc[nn][r] + bv;
            if (rrow < n) {
                hout[(size_t)rrow * D + f] = f2h(v);
                s += v;
                q += v * v;
            }
        }
        s += __shfl_xor(s, 16); q += __shfl_xor(q, 16);
        s += __shfl_xor(s, 32); q += __shfl_xor(q, 32);
        if (lane < 16) {
            red[wave][f] = s;
            red[wave][96 + f] = q;
        }
    }
    __syncthreads();
    if (tid < 192) {
        float t = red[0][tid] + red[1][tid] + red[2][tid] + red[3][tid];
        atomicAdd(&stats[(blockIdx.x & (NREP - 1)) * 2 * D + tid], t);
    }
}

// fused final BN+ReLU + classifier (reads pre-BN h, writes logits directly)
__global__ void __launch_bounds__(256) apply_clf_kernel(
        const unsigned short* __restrict__ h,      // pre-BN fp16, layer 2
        const float* __restrict__ stats,
        const float* __restrict__ gamma,
        const float* __restrict__ beta,
        const float* __restrict__ W,
        const float* __restrict__ b,
        float* __restrict__ out, int n) {
    __shared__ float sW[D * NC];
    __shared__ float sB[NC];
    __shared__ float sC[2 * D];
    int tid = threadIdx.x;
    bn_fold(stats, gamma, beta, sC, tid);
    for (int i = tid; i < D * NC; i += blockDim.x) sW[i] = W[i];
    if (tid < NC) sB[tid] = b[tid];
    __syncthreads();
    int node = blockIdx.x * blockDim.x + tid;
    if (node >= n) return;
    float acc[NC];
    #pragma unroll
    for (int c = 0; c < NC; ++c) acc[c] = sB[c];
    const uint4* row = (const uint4*)(h + (size_t)node * D);
    #pragma unroll
    for (int q4 = 0; q4 < D / 8; ++q4) {
        uint4 v = row[q4];
        unsigned int* pv = (unsigned int*)&v;
        #pragma unroll
        for (int j = 0; j < 4; ++j) {
            int k = q4 * 8 + j * 2;
            h2t a = __builtin_bit_cast(h2t, pv[j]);
            float x0 = fmaxf(fmaf((float)a.x, sC[k], sC[D + k]), 0.f);
            float x1 = fmaxf(fmaf((float)a.y, sC[k + 1], sC[D + k + 1]), 0.f);
            #pragma unroll
            for (int c = 0; c < NC; ++c)
                acc[c] += x0 * sW[k * NC + c] + x1 * sW[(k + 1) * NC + c];
        }
    }
    float* orow = out + (size_t)node * NC;
    #pragma unroll
    for (int c = 0; c < NC; ++c) orow[c] = acc[c];
}

extern "C" void kernel_launch(void* const* d_in, const int* in_sizes, int n_in,
                              void* d_out, int out_size, void* d_ws, size_t ws_size,
                              hipStream_t stream) {
    const float* x      = (const float*)d_in[0];
    const void*  eidx   = d_in[1];
    const float* w_ngh  = (const float*)d_in[2];
    const float* w_self = (const float*)d_in[3];
    const float* bias   = (const float*)d_in[4];
    const float* gamma  = (const float*)d_in[5];
    const float* beta   = (const float*)d_in[6];
    const float* clf_w  = (const float*)d_in[7];
    const float* clf_b  = (const float*)d_in[8];
    float* out = (float*)d_out;

    char* ws = (char*)d_ws;
    size_t o = 0;
    auto alloc = [&](size_t bytes) -> void* {
        void* r = ws + o;
        o += (bytes + 255) & ~(size_t)255;
        return r;
    };
    int*   flag    = (int*)alloc(4);
    int*   row_ptr = (int*)alloc((size_t)(NN + 1) * 4);
    float* inv_deg = (float*)alloc((size_t)NN * 4);
    int*   csr_src = (int*)alloc((size_t)NE * 4);
    float* stats   = (float*)alloc((size_t)NL * NREP * 2 * D * 4);
    int*   cnt     = (int*)alloc((size_t)NB * 4);
    unsigned short* wt   = (unsigned short*)alloc((size_t)NL * D * WPAD * 2);
    unsigned short* xb   = (unsigned short*)alloc((size_t)NN * D * 2);
    unsigned short* aggb = (unsigned short*)alloc((size_t)NN * D * 2);
    unsigned short* hpre = (unsigned short*)alloc((size_t)NN * D * 2);
    unsigned short* hpA  = (unsigned short*)alloc((size_t)NN * D * 2);
    unsigned short* hpB  = (unsigned short*)alloc((size_t)NN * D * 2);
    // binned bucket regions alias hpA (dead until layer-0 bn_apply writes it)
    unsigned int* binned = (unsigned int*)hpA;   // NB*CAP*4 = 4.8MB <= 9.6MB

    prep_kernel<<<CASTB + PREPWB + 1, 256, 0, stream>>>(
        x, xb, w_ngh, w_self, wt, (const int*)eidx, flag, cnt, stats);
    bin_kernel<<<(NE + EPB - 1) / EPB, 256, 0, stream>>>(eidx, flag, cnt, binned, NE);
    fill_bucket_kernel<<<NB, 256, 0, stream>>>(binned, cnt, row_ptr, inv_deg, csr_src);

    const unsigned short* hin = xb;   // layer input (post-BN for l>0)
    unsigned short* hpost[2] = {hpA, hpB};
    for (int l = 0; l < NL; ++l) {
        agg_kernel<<<(NN * 64 + 255) / 256, 256, 0, stream>>>(
            hin, row_ptr, csr_src, inv_deg, aggb, NN);
        mfma_gemm_kernel<<<(NN + 63) / 64, 256, 0, stream>>>(
            aggb, hin, wt + (size_t)l * D * WPAD, bias + (size_t)l * D,
            hpre, stats + (size_t)l * NREP * 2 * D, NN);
        if (l < NL - 1) {
            bn_apply_kernel<<<(NN * D / 8 + 255) / 256, 256, 0, stream>>>(
                hpre, stats + (size_t)l * NREP * 2 * D,
                gamma + (size_t)l * D, beta + (size_t)l * D, hpost[l]);
            hin = hpost[l];
        }
    }
    apply_clf_kernel<<<(NN + 255) / 256, 256, 0, stream>>>(
        hpre, stats + (size_t)2 * NREP * 2 * D, gamma + (size_t)2 * D,
        beta + (size_t)2 * D, clf_w, clf_b, out, NN);
}

// Round 10
// 169.205 us; speedup vs baseline: 3.6340x; 1.0581x over previous
//
#include <hip/hip_runtime.h>

#define NN 50000
#define NE 800000
#define D 96
#define NL 3
#define NC 10
#define BN_EPS 1e-5f
#define INV_N (1.0f / (float)NN)
#define NB 196          // buckets of 256 dst nodes (dst >> 8)
#define CAP 6144        // max edges per bucket (mean 4082, +32 sigma)
#define EPB 2048        // edges per bin block
#define NREP 16         // stats replication factor (atomic contention)
#define WPAD 200        // padded wt row stride (shorts); 400B keeps 16B alignment
#define CASTB ((NN * D / 4 + 255) / 256)       // 4688
#define PREPWB ((NL * D * 192 + 255) / 256)    // 216

typedef _Float16 f16x8 __attribute__((ext_vector_type(8)));
typedef _Float16 h2t __attribute__((ext_vector_type(2)));
typedef unsigned short u16x8 __attribute__((ext_vector_type(8)));
typedef unsigned int u32x3 __attribute__((ext_vector_type(3)));
typedef float f32x4 __attribute__((ext_vector_type(4)));

// ----------------------------- fp16 helpers ---------------------------------
__device__ __forceinline__ unsigned short f2h(float x) {
    _Float16 h = (_Float16)x;
    return __builtin_bit_cast(unsigned short, h);
}
__device__ __forceinline__ unsigned int pkh2(float lo, float hi) {
    auto r = __builtin_amdgcn_cvt_pkrtz(lo, hi);   // __fp16 ext_vector(2)
    return __builtin_bit_cast(unsigned int, r);
}
__device__ __forceinline__ unsigned int pkadd(unsigned int a, unsigned int b) {
    h2t x = __builtin_bit_cast(h2t, a);
    h2t y = __builtin_bit_cast(h2t, b);
    h2t z = x + y;
    return __builtin_bit_cast(unsigned int, z);
}

// ---------------- edge index access (int32 vs int64 auto-detect) -------------
__device__ __forceinline__ int edge_at(const void* idx, int is64, long long pos) {
    if (is64) return (int)((const long long*)idx)[pos];
    return ((const int*)idx)[pos];
}

// fold NREP stat replicas -> LDS scale/shift (called by every block; L2-hot)
__device__ __forceinline__ void bn_fold(const float* __restrict__ stats,
                                        const float* __restrict__ gamma,
                                        const float* __restrict__ beta,
                                        float* sC, int t) {
    if (t < D) {
        float s = 0.f, q = 0.f;
        #pragma unroll
        for (int r = 0; r < NREP; ++r) {
            s += stats[r * 2 * D + t];
            q += stats[r * 2 * D + D + t];
        }
        float mu = s * INV_N;
        float va = q * INV_N - mu * mu;
        float sc = rsqrtf(va + BN_EPS) * gamma[t];
        sC[t] = sc;
        sC[D + t] = beta[t] - mu * sc;
    }
}

// merged front-end: cast x->fp16 | build padded W_T fp16 | detect + zero
__global__ void __launch_bounds__(256) prep_kernel(
        const float* __restrict__ x, unsigned short* __restrict__ xb,
        const float* __restrict__ wn, const float* __restrict__ ws,
        unsigned short* __restrict__ wt,
        const int* __restrict__ words, int* __restrict__ flag,
        int* __restrict__ cnt, float* __restrict__ stats) {
    int b = blockIdx.x;
    int t = threadIdx.x;
    if (b < CASTB) {
        int i = b * 256 + t;
        if (i < NN * D / 4) {
            float4 v = ((const float4*)x)[i];
            ushort4 o;
            o.x = f2h(v.x); o.y = f2h(v.y); o.z = f2h(v.z); o.w = f2h(v.w);
            ((ushort4*)xb)[i] = o;
        }
        return;
    }
    if (b < CASTB + PREPWB) {
        int i = (b - CASTB) * 256 + t;
        if (i < NL * D * 192) {
            int k = i % 192;
            int col = (i / 192) % D;
            int l = i / (192 * D);
            float v = (k < D) ? wn[(size_t)l * D * D + k * D + col]
                              : ws[(size_t)l * D * D + (k - D) * D + col];
            wt[((size_t)l * D + col) * WPAD + k] = f2h(v);
        }
        return;
    }
    // last block: detect + zeros
    __shared__ int any_nz;
    if (t == 0) any_nz = 0;
    __syncthreads();
    if (words[2 * t + 1] != 0) atomicOr(&any_nz, 1);
    __syncthreads();
    if (t == 0) *flag = any_nz ? 0 : 1;   // 1 => int64
    if (t < NB) cnt[t] = 0;
    for (int i = t; i < NL * NREP * 2 * D; i += 256) stats[i] = 0.f;
}

// bucket edges by dst>>8; write (src<<8)|(dst&255) into per-bucket regions
__global__ void __launch_bounds__(256) bin_kernel(
        const void* __restrict__ idx, const int* __restrict__ flag,
        int* __restrict__ cnt, unsigned int* __restrict__ binned, int E) {
    __shared__ int hist[256];
    __shared__ int gbase[256];
    __shared__ unsigned int pk[EPB];
    __shared__ unsigned char bkt[EPB];
    int t = threadIdx.x;
    int base = blockIdx.x * EPB;
    int is64 = *flag;
    hist[t] = 0;
    __syncthreads();
    #pragma unroll
    for (int j = 0; j < 8; ++j) {
        int i = t + j * 256;
        int e = base + i;
        if (e < E) {
            int s = edge_at(idx, is64, e);
            int d = edge_at(idx, is64, (long long)E + e);
            int b = d >> 8;
            bkt[i] = (unsigned char)b;
            pk[i] = ((unsigned int)s << 8) | (unsigned int)(d & 255);
            atomicAdd(&hist[b], 1);
        } else {
            bkt[i] = 0xFF;
        }
    }
    __syncthreads();
    int h = hist[t];
    int gb = 0;
    if (t < NB && h > 0) gb = atomicAdd(&cnt[t], h);
    gbase[t] = gb;
    hist[t] = 0;
    __syncthreads();
    #pragma unroll
    for (int j = 0; j < 8; ++j) {
        int i = t + j * 256;
        int b = bkt[i];
        if (b != 0xFF) {
            int loc = atomicAdd(&hist[b], 1);
            int pos = gbase[b] + loc;
            if (pos < CAP) binned[(size_t)b * CAP + pos] = pk[i];
        }
    }
}

// per bucket: in-block scan of bucket counts -> base; LDS degree count ->
// scan -> row_ptr/inv_deg; LDS-local CSR scatter; coalesced copy-out
__global__ void __launch_bounds__(256) fill_bucket_kernel(
        const unsigned int* __restrict__ binned, const int* __restrict__ cnt,
        int* __restrict__ row_ptr, float* __restrict__ inv_deg,
        int* __restrict__ csr_src) {
    __shared__ int sexcl[256];
    __shared__ int deg_l[256];
    __shared__ int wsum[4];
    __shared__ int lds_csr[CAP];
    int b = blockIdx.x;
    int t = threadIdx.x;
    int lane = t & 63, w = t >> 6;
    {
        int v = (t < NB) ? cnt[t] : 0;
        int x = v;
        #pragma unroll
        for (int off = 1; off < 64; off <<= 1) {
            int y = __shfl_up(x, off);
            if (lane >= off) x += y;
        }
        if (lane == 63) wsum[w] = x;
        __syncthreads();
        if (t == 0) {
            int r = 0;
            #pragma unroll
            for (int i = 0; i < 4; ++i) { int tt = wsum[i]; wsum[i] = r; r += tt; }
        }
        __syncthreads();
        sexcl[t] = x - v + wsum[w];
        __syncthreads();
    }
    int base = sexcl[b];
    int count = cnt[b]; if (count > CAP) count = CAP;
    int n0 = b << 8;
    deg_l[t] = 0;
    __syncthreads();
    const unsigned int* reg = binned + (size_t)b * CAP;
    for (int i = t; i < count; i += 256) atomicAdd(&deg_l[reg[i] & 255], 1);
    __syncthreads();
    int v = deg_l[t];
    int x = v;
    #pragma unroll
    for (int off = 1; off < 64; off <<= 1) {
        int y = __shfl_up(x, off);
        if (lane >= off) x += y;
    }
    if (lane == 63) wsum[w] = x;
    __syncthreads();
    if (t == 0) {
        int r = 0;
        #pragma unroll
        for (int i = 0; i < 4; ++i) { int tt = wsum[i]; wsum[i] = r; r += tt; }
    }
    __syncthreads();
    int excl = x - v + wsum[w];
    int node = n0 + t;
    if (node < NN) {
        row_ptr[node] = base + excl;
        inv_deg[node] = 1.0f / (float)(v > 0 ? v : 1);
    }
    if (b == 0 && t == 0) row_ptr[NN] = NE;
    deg_l[t] = excl;   // reuse as fill cursor
    __syncthreads();
    for (int i = t; i < count; i += 256) {
        unsigned int pkv = reg[i];
        int loc = atomicAdd(&deg_l[pkv & 255], 1);
        lds_csr[loc] = (int)(pkv >> 8);
    }
    __syncthreads();
    for (int i = t; i < count; i += 256) csr_src[base + i] = lds_csr[i];
}

// materialize post-BN+ReLU fp16 h; BN coefs folded in-block from replicas
__global__ void __launch_bounds__(256) bn_apply_kernel(
        const unsigned short* __restrict__ hpre,
        const float* __restrict__ stats,
        const float* __restrict__ gamma,
        const float* __restrict__ beta,
        unsigned short* __restrict__ hpost) {
    __shared__ float sC[2 * D];
    int t = threadIdx.x;
    bn_fold(stats, gamma, beta, sC, t);
    __syncthreads();
    int i = blockIdx.x * 256 + t;
    if (i >= NN * D / 8) return;
    uint4 v = ((const uint4*)hpre)[i];
    int f0 = (i * 8) % D;
    unsigned int* pv = (unsigned int*)&v;
    uint4 o;
    unsigned int* po = (unsigned int*)&o;
    #pragma unroll
    for (int j = 0; j < 4; ++j) {
        int f = f0 + 2 * j;
        h2t a = __builtin_bit_cast(h2t, pv[j]);
        float x0 = fmaxf(fmaf((float)a.x, sC[f], sC[D + f]), 0.f);
        float x1 = fmaxf(fmaf((float)a.y, sC[f + 1], sC[D + f + 1]), 0.f);
        po[j] = pkh2(x0, x1);
    }
    ((uint4*)hpost)[i] = o;
}

// one wave per dst node: 4 groups x 16 lanes; each group keeps 4 edges in
// flight (16 loads/wave outstanding). Lane owns 12 bytes (6 fp16).
__global__ void agg_kernel(const unsigned short* __restrict__ hb,
                           const int* __restrict__ row_ptr,
                           const int* __restrict__ csr_src,
                           const float* __restrict__ inv_deg,
                           unsigned short* __restrict__ aggb, int n) {
    int gid = blockIdx.x * blockDim.x + threadIdx.x;
    int node = gid >> 6;
    int lane = gid & 63;
    if (node >= n) return;
    int g = lane >> 4;          // edge-slot group 0..3
    unsigned int p12 = (lane & 15) * 12u;
    int beg = row_ptr[node], end = row_ptr[node + 1];
    const char* hbase = (const char*)hb;

    u32x3 a0 = {0,0,0}, a1 = {0,0,0}, a2 = {0,0,0}, a3 = {0,0,0};
    int i0 = (beg + g      < end) ? csr_src[beg + g]      : -1;
    int i1 = (beg + 4 + g  < end) ? csr_src[beg + 4 + g]  : -1;
    int i2 = (beg + 8 + g  < end) ? csr_src[beg + 8 + g]  : -1;
    int i3 = (beg + 12 + g < end) ? csr_src[beg + 12 + g] : -1;
    int e = beg;
    while (e < end) {
        u32x3 u0 = {0,0,0}, u1 = {0,0,0}, u2 = {0,0,0}, u3 = {0,0,0};
        if (i0 >= 0) u0 = *(const u32x3*)(hbase + (unsigned)i0 * 192u + p12);
        if (i1 >= 0) u1 = *(const u32x3*)(hbase + (unsigned)i1 * 192u + p12);
        if (i2 >= 0) u2 = *(const u32x3*)(hbase + (unsigned)i2 * 192u + p12);
        if (i3 >= 0) u3 = *(const u32x3*)(hbase + (unsigned)i3 * 192u + p12);
        int en = e + 16;
        i0 = (en + g      < end) ? csr_src[en + g]      : -1;
        i1 = (en + 4 + g  < end) ? csr_src[en + 4 + g]  : -1;
        i2 = (en + 8 + g  < end) ? csr_src[en + 8 + g]  : -1;
        i3 = (en + 12 + g < end) ? csr_src[en + 12 + g] : -1;
        #pragma unroll
        for (int r = 0; r < 3; ++r) {
            a0[r] = pkadd(a0[r], u0[r]);
            a1[r] = pkadd(a1[r], u1[r]);
            a2[r] = pkadd(a2[r], u2[r]);
            a3[r] = pkadd(a3[r], u3[r]);
        }
        e = en;
    }
    // combine 4 chains + cross-group reduce (lanes L, L+16, L+32, L+48)
    unsigned int acc[3];
    #pragma unroll
    for (int r = 0; r < 3; ++r) {
        unsigned int a = pkadd(pkadd(a0[r], a1[r]), pkadd(a2[r], a3[r]));
        a = pkadd(a, (unsigned int)__shfl_xor((int)a, 16));
        a = pkadd(a, (unsigned int)__shfl_xor((int)a, 32));
        acc[r] = a;
    }
    if (lane < 16) {
        float idg = inv_deg[node];
        u32x3 o;
        #pragma unroll
        for (int r = 0; r < 3; ++r) {
            h2t a = __builtin_bit_cast(h2t, acc[r]);
            o[r] = pkh2((float)a.x * idg, (float)a.y * idg);
        }
        *(u32x3*)((char*)aggb + (unsigned)node * 192u + p12) = o;
    }
}

// MFMA fp16 GEMM + fused BN stats. 2 row-tiles (128 nodes) per block:
// wt staged once, B fragments reused for both tiles.
__global__ void __launch_bounds__(256) mfma_gemm_kernel(
        const unsigned short* __restrict__ aggb,
        const unsigned short* __restrict__ hb,     // post-BN (or xb for l=0)
        const unsigned short* __restrict__ wt,     // [96][WPAD] padded fp16
        const float* __restrict__ bias,
        unsigned short* __restrict__ hout,         // pre-BN fp16
        float* __restrict__ stats,                 // NREP replicas
        int n) {
    __shared__ float red[4][192];
    __shared__ unsigned short sW[D][WPAD];   // 38.4 KB
    int tid = threadIdx.x;
    int wave = tid >> 6;
    int lane = tid & 63;
    int m16 = lane & 15;
    int hi = lane >> 4;
    int rb0 = blockIdx.x * 128 + wave * 16;
    int rb1 = rb0 + 64;

    // 1) A-fragment global loads for both tiles (24 independent b128s)
    int ar0 = rb0 + m16; int ar0c = ar0 < n ? ar0 : n - 1;
    int ar1 = rb1 + m16; int ar1c = ar1 < n ? ar1 : n - 1;
    const unsigned short* ap0 = aggb + (size_t)ar0c * D + hi * 8;
    const unsigned short* hp0 = hb + (size_t)ar0c * D + hi * 8;
    const unsigned short* ap1 = aggb + (size_t)ar1c * D + hi * 8;
    const unsigned short* hp1 = hb + (size_t)ar1c * D + hi * 8;
    f16x8 A0[6], A1[6];
    #pragma unroll
    for (int kk = 0; kk < 3; ++kk) {
        A0[kk] = *reinterpret_cast<const f16x8*>(ap0 + kk * 32);
        A0[3 + kk] = *reinterpret_cast<const f16x8*>(hp0 + kk * 32);
        A1[kk] = *reinterpret_cast<const f16x8*>(ap1 + kk * 32);
        A1[3 + kk] = *reinterpret_cast<const f16x8*>(hp1 + kk * 32);
    }

    // 2) cooperative wt staging: 96 cols x 24 chunks of 16B, coalesced
    #pragma unroll
    for (int c = 0; c < 9; ++c) {
        int i = tid + c * 256;
        int col = i / 24, seg = i % 24;
        *reinterpret_cast<u16x8*>(&sW[col][seg * 8]) =
            *reinterpret_cast<const u16x8*>(wt + (size_t)col * WPAD + seg * 8);
    }
    __syncthreads();

    // 3) MFMA loop, B from LDS, reused for both tiles
    f32x4 acc0[6], acc1[6];
    #pragma unroll
    for (int nn = 0; nn < 6; ++nn) {
        acc0[nn] = (f32x4){0.f, 0.f, 0.f, 0.f};
        acc1[nn] = (f32x4){0.f, 0.f, 0.f, 0.f};
    }
    #pragma unroll
    for (int nn = 0; nn < 6; ++nn) {
        int col = nn * 16 + m16;
        #pragma unroll
        for (int kk = 0; kk < 6; ++kk) {
            f16x8 B = *reinterpret_cast<const f16x8*>(&sW[col][kk * 32 + hi * 8]);
            acc0[nn] = __builtin_amdgcn_mfma_f32_16x16x32_f16(A0[kk], B, acc0[nn], 0, 0, 0);
            acc1[nn] = __builtin_amdgcn_mfma_f32_16x16x32_f16(A1[kk], B, acc1[nn], 0, 0, 0);
        }
    }

    // 4) epilogue: bias, fp16 stores, BN partials (both tiles) -> atomics
    #pragma unroll
    for (int nn = 0; nn < 6; ++nn) {
        int f = nn * 16 + m16;
        float bv = bias[f];
        float s = 0.f, q = 0.f;
        #pragma unroll
        for (int r = 0; r < 4; ++r) {
            int row0 = rb0 + hi * 4 + r;
            float v0 = acc0[nn][r] + bv;
            if (row0 < n) {
                hout[(size_t)row0 * D + f] = f2h(v0);
                s += v0;
                q += v0 * v0;
            }
            int row1 = rb1 + hi * 4 + r;
            float v1 = acc1[nn][r] + bv;
            if (row1 < n) {
                hout[(size_t)row1 * D + f] = f2h(v1);
                s += v1;
                q += v1 * v1;
            }
        }
        s += __shfl_xor(s, 16); q += __shfl_xor(q, 16);
        s += __shfl_xor(s, 32); q += __shfl_xor(q, 32);
        if (lane < 16) {
            red[wave][f] = s;
            red[wave][96 + f] = q;
        }
    }
    __syncthreads();
    if (tid < 192) {
        float t = red[0][tid] + red[1][tid] + red[2][tid] + red[3][tid];
        atomicAdd(&stats[(blockIdx.x & (NREP - 1)) * 2 * D + tid], t);
    }
}

// fused final BN+ReLU + classifier (reads pre-BN h, writes logits directly)
__global__ void __launch_bounds__(256) apply_clf_kernel(
        const unsigned short* __restrict__ h,      // pre-BN fp16, layer 2
        const float* __restrict__ stats,
        const float* __restrict__ gamma,
        const float* __restrict__ beta,
        const float* __restrict__ W,
        const float* __restrict__ b,
        float* __restrict__ out, int n) {
    __shared__ float sW[D * NC];
    __shared__ float sB[NC];
    __shared__ float sC[2 * D];
    int tid = threadIdx.x;
    bn_fold(stats, gamma, beta, sC, tid);
    for (int i = tid; i < D * NC; i += blockDim.x) sW[i] = W[i];
    if (tid < NC) sB[tid] = b[tid];
    __syncthreads();
    int node = blockIdx.x * blockDim.x + tid;
    if (node >= n) return;
    float acc[NC];
    #pragma unroll
    for (int c = 0; c < NC; ++c) acc[c] = sB[c];
    const uint4* row = (const uint4*)(h + (size_t)node * D);
    #pragma unroll
    for (int q4 = 0; q4 < D / 8; ++q4) {
        uint4 v = row[q4];
        unsigned int* pv = (unsigned int*)&v;
        #pragma unroll
        for (int j = 0; j < 4; ++j) {
            int k = q4 * 8 + j * 2;
            h2t a = __builtin_bit_cast(h2t, pv[j]);
            float x0 = fmaxf(fmaf((float)a.x, sC[k], sC[D + k]), 0.f);
            float x1 = fmaxf(fmaf((float)a.y, sC[k + 1], sC[D + k + 1]), 0.f);
            #pragma unroll
            for (int c = 0; c < NC; ++c)
                acc[c] += x0 * sW[k * NC + c] + x1 * sW[(k + 1) * NC + c];
        }
    }
    float* orow = out + (size_t)node * NC;
    #pragma unroll
    for (int c = 0; c < NC; ++c) orow[c] = acc[c];
}

extern "C" void kernel_launch(void* const* d_in, const int* in_sizes, int n_in,
                              void* d_out, int out_size, void* d_ws, size_t ws_size,
                              hipStream_t stream) {
    const float* x      = (const float*)d_in[0];
    const void*  eidx   = d_in[1];
    const float* w_ngh  = (const float*)d_in[2];
    const float* w_self = (const float*)d_in[3];
    const float* bias   = (const float*)d_in[4];
    const float* gamma  = (const float*)d_in[5];
    const float* beta   = (const float*)d_in[6];
    const float* clf_w  = (const float*)d_in[7];
    const float* clf_b  = (const float*)d_in[8];
    float* out = (float*)d_out;

    char* ws = (char*)d_ws;
    size_t o = 0;
    auto alloc = [&](size_t bytes) -> void* {
        void* r = ws + o;
        o += (bytes + 255) & ~(size_t)255;
        return r;
    };
    int*   flag    = (int*)alloc(4);
    int*   row_ptr = (int*)alloc((size_t)(NN + 1) * 4);
    float* inv_deg = (float*)alloc((size_t)NN * 4);
    int*   csr_src = (int*)alloc((size_t)NE * 4);
    float* stats   = (float*)alloc((size_t)NL * NREP * 2 * D * 4);
    int*   cnt     = (int*)alloc((size_t)NB * 4);
    unsigned short* wt   = (unsigned short*)alloc((size_t)NL * D * WPAD * 2);
    unsigned short* xb   = (unsigned short*)alloc((size_t)NN * D * 2);
    unsigned short* aggb = (unsigned short*)alloc((size_t)NN * D * 2);
    unsigned short* hpre = (unsigned short*)alloc((size_t)NN * D * 2);
    unsigned short* hpA  = (unsigned short*)alloc((size_t)NN * D * 2);
    unsigned short* hpB  = (unsigned short*)alloc((size_t)NN * D * 2);
    // binned bucket regions alias hpA (dead until layer-0 bn_apply writes it)
    unsigned int* binned = (unsigned int*)hpA;   // NB*CAP*4 = 4.8MB <= 9.6MB

    prep_kernel<<<CASTB + PREPWB + 1, 256, 0, stream>>>(
        x, xb, w_ngh, w_self, wt, (const int*)eidx, flag, cnt, stats);
    bin_kernel<<<(NE + EPB - 1) / EPB, 256, 0, stream>>>(eidx, flag, cnt, binned, NE);
    fill_bucket_kernel<<<NB, 256, 0, stream>>>(binned, cnt, row_ptr, inv_deg, csr_src);

    const unsigned short* hin = xb;   // layer input (post-BN for l>0)
    unsigned short* hpost[2] = {hpA, hpB};
    for (int l = 0; l < NL; ++l) {
        agg_kernel<<<(NN * 64 + 255) / 256, 256, 0, stream>>>(
            hin, row_ptr, csr_src, inv_deg, aggb, NN);
        mfma_gemm_kernel<<<(NN + 127) / 128, 256, 0, stream>>>(
            aggb, hin, wt + (size_t)l * D * WPAD, bias + (size_t)l * D,
            hpre, stats + (size_t)l * NREP * 2 * D, NN);
        if (l < NL - 1) {
            bn_apply_kernel<<<(NN * D / 8 + 255) / 256, 256, 0, stream>>>(
                hpre, stats + (size_t)l * NREP * 2 * D,
                gamma + (size_t)l * D, beta + (size_t)l * D, hpost[l]);
            hin = hpost[l];
        }
    }
    apply_clf_kernel<<<(NN + 255) / 256, 256, 0, stream>>>(
        hpre, stats + (size_t)2 * NREP * 2 * D, gamma + (size_t)2 * D,
        beta + (size_t)2 * D, clf_w, clf_b, out, NN);
}